// Round 11
// baseline (377.372 us; speedup 1.0000x reference)
//
#include <hip/hip_runtime.h>
#include <stdint.h>
#include <stddef.h>

#define N_NODES   100000
#define N_EDGES   3200000
#define F_IN      512
#define HIDDEN    16
#define N_CLASSES 32

#define BSHIFT 6                        // 64 nodes per bucket
#define NBUK   ((N_NODES + 63) >> 6)    // 1563
#define CAP    2368                     // mean 2048, sigma ~45 -> +7 sigma
#define TILE   8192                     // edges per binning block
#define NB_BIN ((N_EDGES + TILE - 1) / TILE)      // 391
#define NW_MASK ((N_NODES * F_IN) / 32)           // 1,600,000 mask words
#define NB_MSK (NW_MASK / 256)                    // 6250
#define NB_G1M ((N_NODES + 127) / 128)            // 782 (128 nodes/block)

// ---------------- Threefry-2x32, JAX-compatible (20 rounds) ----------------
__host__ __device__ __forceinline__ uint32_t rotl32(uint32_t x, int r) {
#ifdef __HIP_DEVICE_COMPILE__
  return __builtin_amdgcn_alignbit(x, x, (uint32_t)(32 - r));  // 1 op
#else
  return (x << r) | (x >> (32 - r));
#endif
}

__host__ __device__ __forceinline__ void tf2x32_full(uint32_t k0, uint32_t k1,
                                                     uint32_t x0, uint32_t x1,
                                                     uint32_t* o0, uint32_t* o1) {
  const uint32_t k2 = k0 ^ k1 ^ 0x1BD11BDAu;
  x0 += k0; x1 += k1;
#define TF_R(r) { x0 += x1; x1 = rotl32(x1, (r)); x1 ^= x0; }
  TF_R(13) TF_R(15) TF_R(26) TF_R(6)   x0 += k1; x1 += k2 + 1u;
  TF_R(17) TF_R(29) TF_R(16) TF_R(24)  x0 += k2; x1 += k0 + 2u;
  TF_R(13) TF_R(15) TF_R(26) TF_R(6)   x0 += k0; x1 += k1 + 3u;
  TF_R(17) TF_R(29) TF_R(16) TF_R(24)  x0 += k1; x1 += k2 + 4u;
  TF_R(13) TF_R(15) TF_R(26) TF_R(6)   x0 += k2; x1 += k0 + 5u;
#undef TF_R
  *o0 = x0; *o1 = x1;
}

// JAX partitionable random_bits(32): bits = out0 ^ out1 of tf(key; 0, idx).
// keep ⟺ uniform < 0.5 ⟺ MSB(bits)==0.
__device__ __forceinline__ bool keep_bit(uint32_t k0, uint32_t k1, uint32_t ctr) {
  uint32_t o0, o1;
  tf2x32_full(k0, k1, 0u, ctr, &o0, &o1);
  return (int32_t)(o0 ^ o1) >= 0;
}

// ---------------- k1: dropout1 mask words (pure threefry, ~full VALU) ------
// word m covers elements m*32..m*32+31 (LSB-first), element = node*512 + f.
__launch_bounds__(256)
__global__ void mask_gen(uint32_t* __restrict__ mask1, uint32_t kd0, uint32_t kd1) {
  const int mt = blockIdx.x * 256 + threadIdx.x;
  if (mt >= NW_MASK) return;
  const uint32_t base = (uint32_t)mt * 32u;
  uint32_t word = 0u;
#pragma unroll
  for (int j = 0; j < 32; j++) {
    uint32_t o0, o1;
    tf2x32_full(kd0, kd1, 0u, base + (uint32_t)j, &o0, &o1);
    word |= ((~(o0 ^ o1)) >> 31) << j;   // MSB==0 -> keep
  }
  mask1[mt] = word;
}

// ---------------- k2: [0..NB_BIN) bin_edges | [NB_BIN..) gemm1(mask) -------
// gemm1: 4 threads per node-pair-slot (K-split over f), 128 nodes/block
// (2 nodes per thread: A = slot, B = slot+64) -> each W1 LDS read feeds 2 FMAs,
// halving LDS traffic. W1 in LDS w/ 2-bit XOR chunk swizzle (conflict-free).
__launch_bounds__(256)
__global__ void bin_gemm1_fused(const float* __restrict__ X,
                                const float* __restrict__ W1,
                                const uint32_t* __restrict__ mask1,
                                float* __restrict__ H1,
                                const int* __restrict__ src, const int* __restrict__ dst,
                                const float* __restrict__ w, int* __restrict__ gcur,
                                int2* __restrict__ ep) {
  __shared__ __align__(16) float smem[F_IN * HIDDEN];  // 32 KB union
  const int tid = threadIdx.x;

  if (blockIdx.x < NB_BIN) {
    // ================= bin_edges path =================
    int* lh = (int*)smem;                 // [NBUK] hist, then local cursor
    int* gb = (int*)smem + NBUK;          // [NBUK] per-tile range base
    const int base = blockIdx.x * TILE;
    const int n = min(TILE, N_EDGES - base);

    for (int i = tid; i < NBUK; i += 256) lh[i] = 0;
    __syncthreads();

    for (int i = tid; i < n; i += 256)
      atomicAdd(&lh[dst[base + i] >> BSHIFT], 1);
    __syncthreads();

    for (int b = tid; b < NBUK; b += 256) {
      const int h = lh[b];
      gb[b] = h ? atomicAdd(&gcur[b], h) : 0;
      lh[b] = 0;  // owned by exactly one thread here; reuse as cursor
    }
    __syncthreads();

    for (int i = tid; i < n; i += 256) {
      const int e = base + i;
      const int d = dst[e];
      const int b = d >> BSHIFT;
      const int pos = gb[b] + atomicAdd(&lh[b], 1);
      if (pos < CAP)
        ep[(size_t)b * CAP + pos] =
            make_int2(src[e] | ((d & 63) << 17), __float_as_int(w[e]));
    }
    return;
  }

  // ================= gemm1 path =================
  float* W1s = smem;  // chunk m of row f stored at pos m^((f>>2)&3)
  for (int i = tid; i < (F_IN * HIDDEN) / 4; i += 256) {
    const int f = i >> 2, m = i & 3;
    ((float4*)W1s)[f * 4 + (m ^ ((f >> 2) & 3))] = ((const float4*)W1)[i];
  }
  __syncthreads();

  const int p = tid & 3;                       // K-quarter
  const int slot = tid >> 2;                   // 0..63
  const int nA = (blockIdx.x - NB_BIN) * 128 + slot;
  const int nB = nA + 64;
  const bool okA = nA < N_NODES, okB = nB < N_NODES;
  const int nAc = okA ? nA : 0, nBc = okB ? nB : 0;

  float accA[16], accB[16];
#pragma unroll
  for (int j = 0; j < 16; j++) { accA[j] = 0.0f; accB[j] = 0.0f; }

  const float4* XA = (const float4*)(X + (size_t)nAc * F_IN);
  const float4* XB = (const float4*)(X + (size_t)nBc * F_IN);
  const uint32_t* MA = mask1 + (size_t)nAc * 16;
  const uint32_t* MB = mask1 + (size_t)nBc * 16;
  const int sh0 = p << 2;          // low half (even sub-iter)
  const int sh1 = 16 + (p << 2);   // high half

  for (int it2 = 0; it2 < 16; ++it2) {
    const uint32_t mwA = MA[it2], mwB = MB[it2];
    const float4 xa0 = XA[it2 * 8 + p],     xa1 = XA[it2 * 8 + 4 + p];
    const float4 xb0 = XB[it2 * 8 + p],     xb1 = XB[it2 * 8 + 4 + p];
    const float a0[4] = {xa0.x, xa0.y, xa0.z, xa0.w};
    const float a1[4] = {xa1.x, xa1.y, xa1.z, xa1.w};
    const float b0[4] = {xb0.x, xb0.y, xb0.z, xb0.w};
    const float b1[4] = {xb1.x, xb1.y, xb1.z, xb1.w};

#pragma unroll
    for (int e = 0; e < 4; e++) {
      const float xdA = ((mwA >> (sh0 + e)) & 1u) ? a0[e] + a0[e] : 0.0f;
      const float xdB = ((mwB >> (sh0 + e)) & 1u) ? b0[e] + b0[e] : 0.0f;
      const int f = it2 * 32 + p * 4 + e;
      const float4* row = (const float4*)&W1s[f * 16];
#pragma unroll
      for (int q = 0; q < 4; q++) {
        const float4 wv = row[q ^ p];
        accA[q * 4 + 0] += xdA * wv.x;  accB[q * 4 + 0] += xdB * wv.x;
        accA[q * 4 + 1] += xdA * wv.y;  accB[q * 4 + 1] += xdB * wv.y;
        accA[q * 4 + 2] += xdA * wv.z;  accB[q * 4 + 2] += xdB * wv.z;
        accA[q * 4 + 3] += xdA * wv.w;  accB[q * 4 + 3] += xdB * wv.w;
      }
    }
#pragma unroll
    for (int e = 0; e < 4; e++) {
      const float xdA = ((mwA >> (sh1 + e)) & 1u) ? a1[e] + a1[e] : 0.0f;
      const float xdB = ((mwB >> (sh1 + e)) & 1u) ? b1[e] + b1[e] : 0.0f;
      const int f = it2 * 32 + 16 + p * 4 + e;
      const float4* row = (const float4*)&W1s[f * 16];
#pragma unroll
      for (int q = 0; q < 4; q++) {
        const float4 wv = row[q ^ p];
        accA[q * 4 + 0] += xdA * wv.x;  accB[q * 4 + 0] += xdB * wv.x;
        accA[q * 4 + 1] += xdA * wv.y;  accB[q * 4 + 1] += xdB * wv.y;
        accA[q * 4 + 2] += xdA * wv.z;  accB[q * 4 + 2] += xdB * wv.z;
        accA[q * 4 + 3] += xdA * wv.w;  accB[q * 4 + 3] += xdB * wv.w;
      }
    }
  }

  // cross-p reduce (4 lanes per node); value-selects keep reg indices static
#define CROSSP_REDUCE(ACC, OK, NODE)                                     \
  {                                                                      \
    float a2[8];                                                         \
    _Pragma("unroll")                                                    \
    for (int k = 0; k < 8; k++) {                                        \
      const float keep = (p & 2) ? ACC[8 + k] : ACC[k];                  \
      const float send = (p & 2) ? ACC[k]     : ACC[8 + k];              \
      a2[k] = keep + __shfl_xor(send, 2);                                \
    }                                                                    \
    float r0, r1, r2, r3;                                                \
    {                                                                    \
      const float k0v = (p & 1) ? a2[4] : a2[0];                         \
      const float s0v = (p & 1) ? a2[0] : a2[4];                         \
      r0 = k0v + __shfl_xor(s0v, 1);                                     \
      const float k1v = (p & 1) ? a2[5] : a2[1];                         \
      const float s1v = (p & 1) ? a2[1] : a2[5];                         \
      r1 = k1v + __shfl_xor(s1v, 1);                                     \
      const float k2v = (p & 1) ? a2[6] : a2[2];                         \
      const float s2v = (p & 1) ? a2[2] : a2[6];                         \
      r2 = k2v + __shfl_xor(s2v, 1);                                     \
      const float k3v = (p & 1) ? a2[7] : a2[3];                         \
      const float s3v = (p & 1) ? a2[3] : a2[7];                         \
      r3 = k3v + __shfl_xor(s3v, 1);                                     \
    }                                                                    \
    if (OK)                                                              \
      *(float4*)(H1 + (size_t)(NODE) * HIDDEN + p * 4) =                 \
          make_float4(r0, r1, r2, r3);                                   \
  }

  CROSSP_REDUCE(accA, okA, nA)
  CROSSP_REDUCE(accB, okB, nB)
#undef CROSSP_REDUCE
}

// ---------------- gather1: H2d = dropout2(relu(A @ H1)) [N,16] ----------------
__launch_bounds__(256)
__global__ void bucket_gather1(const int* __restrict__ gcur, const int2* __restrict__ ep,
                               const float* __restrict__ H1, float* __restrict__ H2d,
                               uint32_t k0, uint32_t k1) {
  __shared__ int2 B[CAP];                // 18.5 KB
  __shared__ int lh[64], lex[64], lcur[64];
  const int tid = threadIdx.x;
  const int b = blockIdx.x;

  if (tid < 64) lh[tid] = 0;
  __syncthreads();

  const int c = min(gcur[b], CAP);
  const int2* ebase = ep + (size_t)b * CAP;

  for (int k = tid; k < c; k += 256)
    atomicAdd(&lh[(ebase[k].x >> 17) & 63], 1);
  __syncthreads();

  if (tid < 64) {  // wave 0: 64-lane exclusive scan
    const int v = lh[tid];
    int s = v;
    for (int off = 1; off < 64; off <<= 1) {
      const int t = __shfl_up(s, off);
      if (tid >= off) s += t;
    }
    lex[tid] = s - v;
    lcur[tid] = s - v;
  }
  __syncthreads();

  for (int k = tid; k < c; k += 256) {
    const int2 r = ebase[k];
    const int p = atomicAdd(&lcur[(r.x >> 17) & 63], 1);
    B[p] = r;
  }
  __syncthreads();

  const int lane = tid & 63, wid = tid >> 6;
  const int ei = lane >> 4, f = lane & 15;
  for (int ln = wid; ln < 64; ln += 4) {
    const int ng = (b << BSHIFT) + ln;
    if (ng >= N_NODES) break;
    const int beg = lex[ln], cnt = lh[ln];
    float acc = 0.0f;
    for (int k = beg + ei; k < beg + cnt; k += 4) {
      const int2 r = B[k];
      acc += __int_as_float(r.y) * H1[(size_t)(r.x & 0x1FFFF) * HIDDEN + f];
    }
    acc += __shfl_xor(acc, 16);
    acc += __shfl_xor(acc, 32);
    // relu + dropout2 (mask over [N,16], idx = ng*16 + f)
    float v = fmaxf(acc, 0.0f);
    v = keep_bit(k0, k1, (uint32_t)ng * HIDDEN + (uint32_t)f) ? v * 2.0f : 0.0f;
    if (lane < 16) H2d[(size_t)ng * HIDDEN + f] = v;
  }
}

// ---------------- gather2: out = softmax((A @ H2d) @ W2) [N,32] ----------------
__launch_bounds__(256)
__global__ void bucket_gather2(const int* __restrict__ gcur, const int2* __restrict__ ep,
                               const float* __restrict__ H2d, const float* __restrict__ W2,
                               float* __restrict__ O) {
  __shared__ int2 B[CAP];
  __shared__ float W2s[HIDDEN][N_CLASSES];  // 2 KB
  __shared__ int lh[64], lex[64], lcur[64];
  const int tid = threadIdx.x;
  const int b = blockIdx.x;

  if (tid < 64) lh[tid] = 0;
  for (int i = tid; i < HIDDEN * N_CLASSES; i += 256) ((float*)W2s)[i] = W2[i];
  __syncthreads();

  const int c = min(gcur[b], CAP);
  const int2* ebase = ep + (size_t)b * CAP;

  for (int k = tid; k < c; k += 256)
    atomicAdd(&lh[(ebase[k].x >> 17) & 63], 1);
  __syncthreads();

  if (tid < 64) {
    const int v = lh[tid];
    int s = v;
    for (int off = 1; off < 64; off <<= 1) {
      const int t = __shfl_up(s, off);
      if (tid >= off) s += t;
    }
    lex[tid] = s - v;
    lcur[tid] = s - v;
  }
  __syncthreads();

  for (int k = tid; k < c; k += 256) {
    const int2 r = ebase[k];
    const int p = atomicAdd(&lcur[(r.x >> 17) & 63], 1);
    B[p] = r;
  }
  __syncthreads();

  const int lane = tid & 63, wid = tid >> 6;
  const int ei = lane >> 4, f = lane & 15;
  const int cl = lane & 31;
  for (int ln = wid; ln < 64; ln += 4) {
    const int ng = (b << BSHIFT) + ln;
    if (ng >= N_NODES) break;
    const int beg = lex[ln], cnt = lh[ln];
    float acc = 0.0f;
    for (int k = beg + ei; k < beg + cnt; k += 4) {
      const int2 r = B[k];
      acc += __int_as_float(r.y) * H2d[(size_t)(r.x & 0x1FFFF) * HIDDEN + f];
    }
    acc += __shfl_xor(acc, 16);
    acc += __shfl_xor(acc, 32);   // every lane now holds G2[ng][lane&15]
    // logits: c = lane&31 ; lg = sum_f G2[f] * W2[f][c]
    float lg = 0.0f;
#pragma unroll
    for (int fq = 0; fq < HIDDEN; fq++)
      lg += __shfl(acc, fq) * W2s[fq][cl];
    // softmax across the 32-lane group
    float m = lg;
#pragma unroll
    for (int off = 16; off >= 1; off >>= 1) m = fmaxf(m, __shfl_xor(m, off));
    const float ex = __expf(lg - m);
    float ss = ex;
#pragma unroll
    for (int off = 16; off >= 1; off >>= 1) ss += __shfl_xor(ss, off);
    if (lane < 32) O[(size_t)ng * N_CLASSES + cl] = ex / ss;
  }
}

// ================= fallback atomic path (small ws) =================
__launch_bounds__(256)
__global__ void gemm1_dropout_fb(const float* __restrict__ X,
                                 const float* __restrict__ W1,
                                 float* __restrict__ H1,
                                 uint32_t kd0, uint32_t kd1) {
  __shared__ float W1s[F_IN][HIDDEN];
  const int tid = threadIdx.x;
  for (int i = tid; i < (F_IN * HIDDEN) / 4; i += 256)
    ((float4*)W1s)[i] = ((const float4*)W1)[i];
  __syncthreads();
  const int n = blockIdx.x * 256 + tid;
  if (n >= N_NODES) return;
  float acc[HIDDEN];
#pragma unroll
  for (int j = 0; j < HIDDEN; j++) acc[j] = 0.0f;
  const float4* Xrow = (const float4*)(X + (size_t)n * F_IN);
  const uint32_t jbase = (uint32_t)n * F_IN;
  for (int cc = 0; cc < F_IN / 4; cc++) {
    float4 xv = Xrow[cc];
    float xs[4] = {xv.x, xv.y, xv.z, xv.w};
#pragma unroll
    for (int e = 0; e < 4; e++) {
      const int f = cc * 4 + e;
      const float x = keep_bit(kd0, kd1, jbase + (uint32_t)f) ? xs[e] * 2.0f : 0.0f;
      const float* wr = W1s[f];
#pragma unroll
      for (int j = 0; j < HIDDEN; j++) acc[j] += x * wr[j];
    }
  }
  float4* out = (float4*)(H1 + (size_t)n * HIDDEN);
#pragma unroll
  for (int q = 0; q < HIDDEN / 4; q++)
    out[q] = make_float4(acc[q * 4], acc[q * 4 + 1], acc[q * 4 + 2], acc[q * 4 + 3]);
}

__launch_bounds__(256)
__global__ void spmm1_atomic(const int* __restrict__ src, const int* __restrict__ dst,
                             const float* __restrict__ w, const float* __restrict__ H1,
                             float* __restrict__ H2) {
  const long long t = (long long)blockIdx.x * 256 + threadIdx.x;
  if (t >= (long long)N_EDGES * 4) return;
  const int e = (int)(t >> 2);
  const int q = (int)(t & 3);
  const float we = w[e];
  const float4 h = ((const float4*)(H1 + (size_t)src[e] * HIDDEN))[q];
  float* o = H2 + (size_t)dst[e] * HIDDEN + q * 4;
  unsafeAtomicAdd(o + 0, we * h.x);
  unsafeAtomicAdd(o + 1, we * h.y);
  unsafeAtomicAdd(o + 2, we * h.z);
  unsafeAtomicAdd(o + 3, we * h.w);
}

__launch_bounds__(256)
__global__ void gemm2_dropout(const float* __restrict__ H2,
                              const float* __restrict__ W2,
                              float* __restrict__ H3,
                              uint32_t kd0, uint32_t kd1) {
  __shared__ float W2s[HIDDEN][N_CLASSES];
  const int tid = threadIdx.x;
  for (int i = tid; i < (HIDDEN * N_CLASSES) / 4; i += 256)
    ((float4*)W2s)[i] = ((const float4*)W2)[i];
  __syncthreads();
  const int n = blockIdx.x * 256 + tid;
  if (n >= N_NODES) return;
  float acc[N_CLASSES];
#pragma unroll
  for (int j = 0; j < N_CLASSES; j++) acc[j] = 0.0f;
  const float4* hrow = (const float4*)(H2 + (size_t)n * HIDDEN);
  const uint32_t jbase = (uint32_t)n * HIDDEN;
#pragma unroll
  for (int qq = 0; qq < HIDDEN / 4; qq++) {
    float4 hv = hrow[qq];
    float hs[4] = {hv.x, hv.y, hv.z, hv.w};
#pragma unroll
    for (int e = 0; e < 4; e++) {
      const int cc = qq * 4 + e;
      float h = fmaxf(hs[e], 0.0f);
      h = keep_bit(kd0, kd1, jbase + (uint32_t)cc) ? h * 2.0f : 0.0f;
      const float* wr = W2s[cc];
#pragma unroll
      for (int j = 0; j < N_CLASSES; j++) acc[j] += h * wr[j];
    }
  }
  float4* out = (float4*)(H3 + (size_t)n * N_CLASSES);
#pragma unroll
  for (int q = 0; q < N_CLASSES / 4; q++)
    out[q] = make_float4(acc[q * 4], acc[q * 4 + 1], acc[q * 4 + 2], acc[q * 4 + 3]);
}

__launch_bounds__(256)
__global__ void spmm2_atomic(const int* __restrict__ src, const int* __restrict__ dst,
                             const float* __restrict__ w, const float* __restrict__ H3,
                             float* __restrict__ O) {
  const long long t = (long long)blockIdx.x * 256 + threadIdx.x;
  if (t >= (long long)N_EDGES * 8) return;
  const int e = (int)(t >> 3);
  const int q = (int)(t & 7);
  const float we = w[e];
  const float4 h = ((const float4*)(H3 + (size_t)src[e] * N_CLASSES))[q];
  float* o = O + (size_t)dst[e] * N_CLASSES + q * 4;
  unsafeAtomicAdd(o + 0, we * h.x);
  unsafeAtomicAdd(o + 1, we * h.y);
  unsafeAtomicAdd(o + 2, we * h.z);
  unsafeAtomicAdd(o + 3, we * h.w);
}

__launch_bounds__(256)
__global__ void softmax_rows(float* __restrict__ O) {
  const int n = blockIdx.x * 256 + threadIdx.x;
  if (n >= N_NODES) return;
  float4* row = (float4*)(O + (size_t)n * N_CLASSES);
  float v[N_CLASSES];
#pragma unroll
  for (int q = 0; q < N_CLASSES / 4; q++) {
    float4 t = row[q];
    v[q * 4 + 0] = t.x; v[q * 4 + 1] = t.y; v[q * 4 + 2] = t.z; v[q * 4 + 3] = t.w;
  }
  float m = v[0];
#pragma unroll
  for (int j = 1; j < N_CLASSES; j++) m = fmaxf(m, v[j]);
  float s = 0.0f;
#pragma unroll
  for (int j = 0; j < N_CLASSES; j++) { v[j] = __expf(v[j] - m); s += v[j]; }
  const float inv = 1.0f / s;
#pragma unroll
  for (int q = 0; q < N_CLASSES / 4; q++)
    row[q] = make_float4(v[q * 4] * inv, v[q * 4 + 1] * inv,
                         v[q * 4 + 2] * inv, v[q * 4 + 3] * inv);
}

// ---------------- host ----------------
extern "C" void kernel_launch(void* const* d_in, const int* in_sizes, int n_in,
                              void* d_out, int out_size, void* d_ws, size_t ws_size,
                              hipStream_t stream) {
  const float* X    = (const float*)d_in[0];
  const int*   esrc = (const int*)d_in[1];
  const int*   edst = (const int*)d_in[2];
  const float* ew   = (const float*)d_in[3];
  const float* W1   = (const float*)d_in[4];
  const float* W2   = (const float*)d_in[5];
  float* out = (float*)d_out;

  // JAX: key = random.key(42); kd1, kd2 = random.split(key)  (partitionable)
  uint32_t kd1_0, kd1_1, kd2_0, kd2_1;
  tf2x32_full(0u, 42u, 0u, 0u, &kd1_0, &kd1_1);
  tf2x32_full(0u, 42u, 0u, 1u, &kd2_0, &kd2_1);

  const int nb_nodes = (N_NODES + 255) / 256;       // 391 (fallback kernels)

  // workspace: ep | H1 | H2d | mask1 | gcur
  const size_t sz_ep  = (size_t)NBUK * CAP * sizeof(int2);          // 29.6 MB
  const size_t sz_H1  = (size_t)N_NODES * HIDDEN * sizeof(float);   // 6.4 MB
  const size_t sz_H2d = sz_H1;                                      // 6.4 MB
  const size_t sz_mk  = (size_t)NW_MASK * sizeof(uint32_t);         // 6.4 MB
  const size_t sz_cur = (size_t)NBUK * sizeof(int);
  const size_t need = sz_ep + sz_H1 + sz_H2d + sz_mk + sz_cur;      // ~48.9 MB

  char* p = (char*)d_ws;
  int2* ep = (int2*)p;       p += sz_ep;
  float* H1 = (float*)p;     p += sz_H1;
  float* H2d = (float*)p;    p += sz_H2d;
  uint32_t* mask1 = (uint32_t*)p; p += sz_mk;
  int* gcur = (int*)p;

  if (ws_size >= need) {
    hipMemsetAsync(gcur, 0, sz_cur, stream);
    mask_gen<<<NB_MSK, 256, 0, stream>>>(mask1, kd1_0, kd1_1);
    bin_gemm1_fused<<<NB_BIN + NB_G1M, 256, 0, stream>>>(
        X, W1, mask1, H1, esrc, edst, ew, gcur, ep);
    bucket_gather1<<<NBUK, 256, 0, stream>>>(gcur, ep, H1, H2d, kd2_0, kd2_1);
    bucket_gather2<<<NBUK, 256, 0, stream>>>(gcur, ep, H2d, W2, out);
  } else {
    // fallback: atomic path (25.6 MB)
    float* fH1 = (float*)d_ws;
    float* fH2 = fH1 + (size_t)N_NODES * HIDDEN;
    float* fH3 = fH2 + (size_t)N_NODES * HIDDEN;
    hipMemsetAsync(fH2, 0, (size_t)N_NODES * HIDDEN * sizeof(float), stream);
    hipMemsetAsync(out, 0, (size_t)out_size * sizeof(float), stream);
    gemm1_dropout_fb<<<nb_nodes, 256, 0, stream>>>(X, W1, fH1, kd1_0, kd1_1);
    spmm1_atomic<<<(N_EDGES * 4) / 256, 256, 0, stream>>>(esrc, edst, ew, fH1, fH2);
    gemm2_dropout<<<nb_nodes, 256, 0, stream>>>(fH2, W2, fH3, kd2_0, kd2_1);
    spmm2_atomic<<<(N_EDGES * 8) / 256, 256, 0, stream>>>(esrc, edst, ew, fH3, out);
    softmax_rows<<<nb_nodes, 256, 0, stream>>>(out);
  }
}

// Round 12
// 354.564 us; speedup vs baseline: 1.0643x; 1.0643x over previous
//
#include <hip/hip_runtime.h>
#include <stdint.h>
#include <stddef.h>

#define N_NODES   100000
#define N_EDGES   3200000
#define F_IN      512
#define HIDDEN    16
#define N_CLASSES 32

#define BSHIFT 6                        // 64 nodes per bucket
#define NBUK   ((N_NODES + 63) >> 6)    // 1563
#define CAP    2368                     // mean 2048, sigma ~45 -> +7 sigma
#define TILE   8192                     // edges per binning block
#define NB_BIN ((N_EDGES + TILE - 1) / TILE)      // 391
#define NW_MASK ((N_NODES * F_IN) / 32)           // 1,600,000 mask words
#define NB_MSK (NW_MASK / 256)                    // 6250
#define NB_G1  ((N_NODES + 63) / 64)              // 1563 (64 nodes/block)

// ---------------- Threefry-2x32, JAX-compatible (20 rounds) ----------------
__host__ __device__ __forceinline__ uint32_t rotl32(uint32_t x, int r) {
#ifdef __HIP_DEVICE_COMPILE__
  return __builtin_amdgcn_alignbit(x, x, (uint32_t)(32 - r));  // 1 op
#else
  return (x << r) | (x >> (32 - r));
#endif
}

__host__ __device__ __forceinline__ void tf2x32_full(uint32_t k0, uint32_t k1,
                                                     uint32_t x0, uint32_t x1,
                                                     uint32_t* o0, uint32_t* o1) {
  const uint32_t k2 = k0 ^ k1 ^ 0x1BD11BDAu;
  x0 += k0; x1 += k1;
#define TF_R(r) { x0 += x1; x1 = rotl32(x1, (r)); x1 ^= x0; }
  TF_R(13) TF_R(15) TF_R(26) TF_R(6)   x0 += k1; x1 += k2 + 1u;
  TF_R(17) TF_R(29) TF_R(16) TF_R(24)  x0 += k2; x1 += k0 + 2u;
  TF_R(13) TF_R(15) TF_R(26) TF_R(6)   x0 += k0; x1 += k1 + 3u;
  TF_R(17) TF_R(29) TF_R(16) TF_R(24)  x0 += k1; x1 += k2 + 4u;
  TF_R(13) TF_R(15) TF_R(26) TF_R(6)   x0 += k2; x1 += k0 + 5u;
#undef TF_R
  *o0 = x0; *o1 = x1;
}

// JAX partitionable random_bits(32): bits = out0 ^ out1 of tf(key; 0, idx).
// keep ⟺ uniform < 0.5 ⟺ MSB(bits)==0.
__device__ __forceinline__ bool keep_bit(uint32_t k0, uint32_t k1, uint32_t ctr) {
  uint32_t o0, o1;
  tf2x32_full(k0, k1, 0u, ctr, &o0, &o1);
  return (int32_t)(o0 ^ o1) >= 0;
}

// ---------------- k1: dropout1 mask words (pure threefry, ~full VALU) ------
// word m covers elements m*32..m*32+31 (LSB-first), element = node*512 + f.
__launch_bounds__(256)
__global__ void mask_gen(uint32_t* __restrict__ mask1, uint32_t kd0, uint32_t kd1) {
  const int mt = blockIdx.x * 256 + threadIdx.x;
  if (mt >= NW_MASK) return;
  const uint32_t base = (uint32_t)mt * 32u;
  uint32_t word = 0u;
#pragma unroll
  for (int j = 0; j < 32; j++) {
    uint32_t o0, o1;
    tf2x32_full(kd0, kd1, 0u, base + (uint32_t)j, &o0, &o1);
    word |= ((~(o0 ^ o1)) >> 31) << j;   // MSB==0 -> keep
  }
  mask1[mt] = word;
}

// ---------------- k2: [0..NB_BIN) bin_edges | [NB_BIN..) gemm1(mask) -------
// gemm1: 4 threads/node (K-split over f), 64 nodes/block (r10's proven body).
// W1 in LDS w/ 2-bit XOR chunk swizzle (conflict-free b128 across p).
// Mask words loaded as uint4 per 4-iteration group (static component refs).
__launch_bounds__(256)
__global__ void bin_gemm1_fused(const float* __restrict__ X,
                                const float* __restrict__ W1,
                                const uint32_t* __restrict__ mask1,
                                float* __restrict__ H1,
                                const int* __restrict__ src, const int* __restrict__ dst,
                                const float* __restrict__ w, int* __restrict__ gcur,
                                int2* __restrict__ ep) {
  __shared__ __align__(16) float smem[F_IN * HIDDEN];  // 32 KB union
  const int tid = threadIdx.x;

  if (blockIdx.x < NB_BIN) {
    // ================= bin_edges path =================
    int* lh = (int*)smem;                 // [NBUK] hist, then local cursor
    int* gb = (int*)smem + NBUK;          // [NBUK] per-tile range base
    const int base = blockIdx.x * TILE;
    const int n = min(TILE, N_EDGES - base);

    for (int i = tid; i < NBUK; i += 256) lh[i] = 0;
    __syncthreads();

    for (int i = tid; i < n; i += 256)
      atomicAdd(&lh[dst[base + i] >> BSHIFT], 1);
    __syncthreads();

    for (int b = tid; b < NBUK; b += 256) {
      const int h = lh[b];
      gb[b] = h ? atomicAdd(&gcur[b], h) : 0;
      lh[b] = 0;  // owned by exactly one thread here; reuse as cursor
    }
    __syncthreads();

    for (int i = tid; i < n; i += 256) {
      const int e = base + i;
      const int d = dst[e];
      const int b = d >> BSHIFT;
      const int pos = gb[b] + atomicAdd(&lh[b], 1);
      if (pos < CAP)
        ep[(size_t)b * CAP + pos] =
            make_int2(src[e] | ((d & 63) << 17), __float_as_int(w[e]));
    }
    return;
  }

  // ================= gemm1 path (1 node per thread-quad) =================
  float* W1s = smem;  // chunk m of row f stored at pos m^((f>>2)&3)
  for (int i = tid; i < (F_IN * HIDDEN) / 4; i += 256) {
    const int f = i >> 2, m = i & 3;
    ((float4*)W1s)[f * 4 + (m ^ ((f >> 2) & 3))] = ((const float4*)W1)[i];
  }
  __syncthreads();

  const int p = tid & 3;                       // K-quarter
  const int node = (blockIdx.x - NB_BIN) * 64 + (tid >> 2);
  if (node >= N_NODES) return;                 // no barriers after this point

  float acc[16];
#pragma unroll
  for (int j = 0; j < 16; j++) acc[j] = 0.0f;

  const float4* Xrow4 = (const float4*)(X + (size_t)node * F_IN);
  const uint4* M4 = (const uint4*)(mask1 + (size_t)node * 16);
  const int sh0 = p << 2;          // low half (even sub-iter)
  const int sh1 = 16 + (p << 2);   // high half

  // one it2 step: 2 float4 X loads + 8 masked FMA-groups against LDS W1
#define PROC(IT2, MWORD)                                              \
  {                                                                   \
    const uint32_t mword = (MWORD);                                   \
    const float4 xv0 = Xrow4[(IT2) * 8 + p];                          \
    const float4 xv1 = Xrow4[(IT2) * 8 + 4 + p];                      \
    const float xs0[4] = {xv0.x, xv0.y, xv0.z, xv0.w};                \
    const float xs1[4] = {xv1.x, xv1.y, xv1.z, xv1.w};                \
    _Pragma("unroll")                                                 \
    for (int e = 0; e < 4; e++) {                                     \
      const float xd = ((mword >> (sh0 + e)) & 1u) ? xs0[e] + xs0[e]  \
                                                   : 0.0f;            \
      const int f = (IT2) * 32 + p * 4 + e;                           \
      const float4* row = (const float4*)&W1s[f * 16];                \
      _Pragma("unroll")                                               \
      for (int q = 0; q < 4; q++) {                                   \
        const float4 wv = row[q ^ p];                                 \
        acc[q * 4 + 0] += xd * wv.x;                                  \
        acc[q * 4 + 1] += xd * wv.y;                                  \
        acc[q * 4 + 2] += xd * wv.z;                                  \
        acc[q * 4 + 3] += xd * wv.w;                                  \
      }                                                               \
    }                                                                 \
    _Pragma("unroll")                                                 \
    for (int e = 0; e < 4; e++) {                                     \
      const float xd = ((mword >> (sh1 + e)) & 1u) ? xs1[e] + xs1[e]  \
                                                   : 0.0f;            \
      const int f = (IT2) * 32 + 16 + p * 4 + e;                      \
      const float4* row = (const float4*)&W1s[f * 16];                \
      _Pragma("unroll")                                               \
      for (int q = 0; q < 4; q++) {                                   \
        const float4 wv = row[q ^ p];                                 \
        acc[q * 4 + 0] += xd * wv.x;                                  \
        acc[q * 4 + 1] += xd * wv.y;                                  \
        acc[q * 4 + 2] += xd * wv.z;                                  \
        acc[q * 4 + 3] += xd * wv.w;                                  \
      }                                                               \
    }                                                                 \
  }

  for (int g = 0; g < 4; ++g) {        // 4 groups x 4 it2 = 16
    const uint4 mw4 = M4[g];
    const int i0 = g * 4;
    PROC(i0 + 0, mw4.x)
    PROC(i0 + 1, mw4.y)
    PROC(i0 + 2, mw4.z)
    PROC(i0 + 3, mw4.w)
  }
#undef PROC

  // cross-p reduce (4 lanes/node); value-selects keep reg indices static
  float a2[8];
#pragma unroll
  for (int k = 0; k < 8; k++) {
    const float keep = (p & 2) ? acc[8 + k] : acc[k];
    const float send = (p & 2) ? acc[k]     : acc[8 + k];
    a2[k] = keep + __shfl_xor(send, 2);
  }
  float r0, r1, r2, r3;
  {
    const float k0v = (p & 1) ? a2[4] : a2[0];
    const float s0v = (p & 1) ? a2[0] : a2[4];
    r0 = k0v + __shfl_xor(s0v, 1);
    const float k1v = (p & 1) ? a2[5] : a2[1];
    const float s1v = (p & 1) ? a2[1] : a2[5];
    r1 = k1v + __shfl_xor(s1v, 1);
    const float k2v = (p & 1) ? a2[6] : a2[2];
    const float s2v = (p & 1) ? a2[2] : a2[6];
    r2 = k2v + __shfl_xor(s2v, 1);
    const float k3v = (p & 1) ? a2[7] : a2[3];
    const float s3v = (p & 1) ? a2[3] : a2[7];
    r3 = k3v + __shfl_xor(s3v, 1);
  }
  *(float4*)(H1 + (size_t)node * HIDDEN + p * 4) = make_float4(r0, r1, r2, r3);
}

// ---------------- gather1: H2d = dropout2(relu(A @ H1)) [N,16] ----------------
__launch_bounds__(256)
__global__ void bucket_gather1(const int* __restrict__ gcur, const int2* __restrict__ ep,
                               const float* __restrict__ H1, float* __restrict__ H2d,
                               uint32_t k0, uint32_t k1) {
  __shared__ int2 B[CAP];                // 18.5 KB
  __shared__ int lh[64], lex[64], lcur[64];
  const int tid = threadIdx.x;
  const int b = blockIdx.x;

  if (tid < 64) lh[tid] = 0;
  __syncthreads();

  const int c = min(gcur[b], CAP);
  const int2* ebase = ep + (size_t)b * CAP;

  for (int k = tid; k < c; k += 256)
    atomicAdd(&lh[(ebase[k].x >> 17) & 63], 1);
  __syncthreads();

  if (tid < 64) {  // wave 0: 64-lane exclusive scan
    const int v = lh[tid];
    int s = v;
    for (int off = 1; off < 64; off <<= 1) {
      const int t = __shfl_up(s, off);
      if (tid >= off) s += t;
    }
    lex[tid] = s - v;
    lcur[tid] = s - v;
  }
  __syncthreads();

  for (int k = tid; k < c; k += 256) {
    const int2 r = ebase[k];
    const int p = atomicAdd(&lcur[(r.x >> 17) & 63], 1);
    B[p] = r;
  }
  __syncthreads();

  const int lane = tid & 63, wid = tid >> 6;
  const int ei = lane >> 4, f = lane & 15;
  for (int ln = wid; ln < 64; ln += 4) {
    const int ng = (b << BSHIFT) + ln;
    if (ng >= N_NODES) break;
    const int beg = lex[ln], cnt = lh[ln];
    float acc = 0.0f;
    for (int k = beg + ei; k < beg + cnt; k += 4) {
      const int2 r = B[k];
      acc += __int_as_float(r.y) * H1[(size_t)(r.x & 0x1FFFF) * HIDDEN + f];
    }
    acc += __shfl_xor(acc, 16);
    acc += __shfl_xor(acc, 32);
    // relu + dropout2 (mask over [N,16], idx = ng*16 + f)
    float v = fmaxf(acc, 0.0f);
    v = keep_bit(k0, k1, (uint32_t)ng * HIDDEN + (uint32_t)f) ? v * 2.0f : 0.0f;
    if (lane < 16) H2d[(size_t)ng * HIDDEN + f] = v;
  }
}

// ---------------- gather2: out = softmax((A @ H2d) @ W2) [N,32] ----------------
__launch_bounds__(256)
__global__ void bucket_gather2(const int* __restrict__ gcur, const int2* __restrict__ ep,
                               const float* __restrict__ H2d, const float* __restrict__ W2,
                               float* __restrict__ O) {
  __shared__ int2 B[CAP];
  __shared__ float W2s[HIDDEN][N_CLASSES];  // 2 KB
  __shared__ int lh[64], lex[64], lcur[64];
  const int tid = threadIdx.x;
  const int b = blockIdx.x;

  if (tid < 64) lh[tid] = 0;
  for (int i = tid; i < HIDDEN * N_CLASSES; i += 256) ((float*)W2s)[i] = W2[i];
  __syncthreads();

  const int c = min(gcur[b], CAP);
  const int2* ebase = ep + (size_t)b * CAP;

  for (int k = tid; k < c; k += 256)
    atomicAdd(&lh[(ebase[k].x >> 17) & 63], 1);
  __syncthreads();

  if (tid < 64) {
    const int v = lh[tid];
    int s = v;
    for (int off = 1; off < 64; off <<= 1) {
      const int t = __shfl_up(s, off);
      if (tid >= off) s += t;
    }
    lex[tid] = s - v;
    lcur[tid] = s - v;
  }
  __syncthreads();

  for (int k = tid; k < c; k += 256) {
    const int2 r = ebase[k];
    const int p = atomicAdd(&lcur[(r.x >> 17) & 63], 1);
    B[p] = r;
  }
  __syncthreads();

  const int lane = tid & 63, wid = tid >> 6;
  const int ei = lane >> 4, f = lane & 15;
  const int cl = lane & 31;
  for (int ln = wid; ln < 64; ln += 4) {
    const int ng = (b << BSHIFT) + ln;
    if (ng >= N_NODES) break;
    const int beg = lex[ln], cnt = lh[ln];
    float acc = 0.0f;
    for (int k = beg + ei; k < beg + cnt; k += 4) {
      const int2 r = B[k];
      acc += __int_as_float(r.y) * H2d[(size_t)(r.x & 0x1FFFF) * HIDDEN + f];
    }
    acc += __shfl_xor(acc, 16);
    acc += __shfl_xor(acc, 32);   // every lane now holds G2[ng][lane&15]
    // logits: c = lane&31 ; lg = sum_f G2[f] * W2[f][c]
    float lg = 0.0f;
#pragma unroll
    for (int fq = 0; fq < HIDDEN; fq++)
      lg += __shfl(acc, fq) * W2s[fq][cl];
    // softmax across the 32-lane group
    float m = lg;
#pragma unroll
    for (int off = 16; off >= 1; off >>= 1) m = fmaxf(m, __shfl_xor(m, off));
    const float ex = __expf(lg - m);
    float ss = ex;
#pragma unroll
    for (int off = 16; off >= 1; off >>= 1) ss += __shfl_xor(ss, off);
    if (lane < 32) O[(size_t)ng * N_CLASSES + cl] = ex / ss;
  }
}

// ================= fallback atomic path (small ws) =================
__launch_bounds__(256)
__global__ void gemm1_dropout_fb(const float* __restrict__ X,
                                 const float* __restrict__ W1,
                                 float* __restrict__ H1,
                                 uint32_t kd0, uint32_t kd1) {
  __shared__ float W1s[F_IN][HIDDEN];
  const int tid = threadIdx.x;
  for (int i = tid; i < (F_IN * HIDDEN) / 4; i += 256)
    ((float4*)W1s)[i] = ((const float4*)W1)[i];
  __syncthreads();
  const int n = blockIdx.x * 256 + tid;
  if (n >= N_NODES) return;
  float acc[HIDDEN];
#pragma unroll
  for (int j = 0; j < HIDDEN; j++) acc[j] = 0.0f;
  const float4* Xrow = (const float4*)(X + (size_t)n * F_IN);
  const uint32_t jbase = (uint32_t)n * F_IN;
  for (int cc = 0; cc < F_IN / 4; cc++) {
    float4 xv = Xrow[cc];
    float xs[4] = {xv.x, xv.y, xv.z, xv.w};
#pragma unroll
    for (int e = 0; e < 4; e++) {
      const int f = cc * 4 + e;
      const float x = keep_bit(kd0, kd1, jbase + (uint32_t)f) ? xs[e] * 2.0f : 0.0f;
      const float* wr = W1s[f];
#pragma unroll
      for (int j = 0; j < HIDDEN; j++) acc[j] += x * wr[j];
    }
  }
  float4* out = (float4*)(H1 + (size_t)n * HIDDEN);
#pragma unroll
  for (int q = 0; q < HIDDEN / 4; q++)
    out[q] = make_float4(acc[q * 4], acc[q * 4 + 1], acc[q * 4 + 2], acc[q * 4 + 3]);
}

__launch_bounds__(256)
__global__ void spmm1_atomic(const int* __restrict__ src, const int* __restrict__ dst,
                             const float* __restrict__ w, const float* __restrict__ H1,
                             float* __restrict__ H2) {
  const long long t = (long long)blockIdx.x * 256 + threadIdx.x;
  if (t >= (long long)N_EDGES * 4) return;
  const int e = (int)(t >> 2);
  const int q = (int)(t & 3);
  const float we = w[e];
  const float4 h = ((const float4*)(H1 + (size_t)src[e] * HIDDEN))[q];
  float* o = H2 + (size_t)dst[e] * HIDDEN + q * 4;
  unsafeAtomicAdd(o + 0, we * h.x);
  unsafeAtomicAdd(o + 1, we * h.y);
  unsafeAtomicAdd(o + 2, we * h.z);
  unsafeAtomicAdd(o + 3, we * h.w);
}

__launch_bounds__(256)
__global__ void gemm2_dropout(const float* __restrict__ H2,
                              const float* __restrict__ W2,
                              float* __restrict__ H3,
                              uint32_t kd0, uint32_t kd1) {
  __shared__ float W2s[HIDDEN][N_CLASSES];
  const int tid = threadIdx.x;
  for (int i = tid; i < (HIDDEN * N_CLASSES) / 4; i += 256)
    ((float4*)W2s)[i] = ((const float4*)W2)[i];
  __syncthreads();
  const int n = blockIdx.x * 256 + tid;
  if (n >= N_NODES) return;
  float acc[N_CLASSES];
#pragma unroll
  for (int j = 0; j < N_CLASSES; j++) acc[j] = 0.0f;
  const float4* hrow = (const float4*)(H2 + (size_t)n * HIDDEN);
  const uint32_t jbase = (uint32_t)n * HIDDEN;
#pragma unroll
  for (int qq = 0; qq < HIDDEN / 4; qq++) {
    float4 hv = hrow[qq];
    float hs[4] = {hv.x, hv.y, hv.z, hv.w};
#pragma unroll
    for (int e = 0; e < 4; e++) {
      const int cc = qq * 4 + e;
      float h = fmaxf(hs[e], 0.0f);
      h = keep_bit(kd0, kd1, jbase + (uint32_t)cc) ? h * 2.0f : 0.0f;
      const float* wr = W2s[cc];
#pragma unroll
      for (int j = 0; j < N_CLASSES; j++) acc[j] += h * wr[j];
    }
  }
  float4* out = (float4*)(H3 + (size_t)n * N_CLASSES);
#pragma unroll
  for (int q = 0; q < N_CLASSES / 4; q++)
    out[q] = make_float4(acc[q * 4], acc[q * 4 + 1], acc[q * 4 + 2], acc[q * 4 + 3]);
}

__launch_bounds__(256)
__global__ void spmm2_atomic(const int* __restrict__ src, const int* __restrict__ dst,
                             const float* __restrict__ w, const float* __restrict__ H3,
                             float* __restrict__ O) {
  const long long t = (long long)blockIdx.x * 256 + threadIdx.x;
  if (t >= (long long)N_EDGES * 8) return;
  const int e = (int)(t >> 3);
  const int q = (int)(t & 7);
  const float we = w[e];
  const float4 h = ((const float4*)(H3 + (size_t)src[e] * N_CLASSES))[q];
  float* o = O + (size_t)dst[e] * N_CLASSES + q * 4;
  unsafeAtomicAdd(o + 0, we * h.x);
  unsafeAtomicAdd(o + 1, we * h.y);
  unsafeAtomicAdd(o + 2, we * h.z);
  unsafeAtomicAdd(o + 3, we * h.w);
}

__launch_bounds__(256)
__global__ void softmax_rows(float* __restrict__ O) {
  const int n = blockIdx.x * 256 + threadIdx.x;
  if (n >= N_NODES) return;
  float4* row = (float4*)(O + (size_t)n * N_CLASSES);
  float v[N_CLASSES];
#pragma unroll
  for (int q = 0; q < N_CLASSES / 4; q++) {
    float4 t = row[q];
    v[q * 4 + 0] = t.x; v[q * 4 + 1] = t.y; v[q * 4 + 2] = t.z; v[q * 4 + 3] = t.w;
  }
  float m = v[0];
#pragma unroll
  for (int j = 1; j < N_CLASSES; j++) m = fmaxf(m, v[j]);
  float s = 0.0f;
#pragma unroll
  for (int j = 0; j < N_CLASSES; j++) { v[j] = __expf(v[j] - m); s += v[j]; }
  const float inv = 1.0f / s;
#pragma unroll
  for (int q = 0; q < N_CLASSES / 4; q++)
    row[q] = make_float4(v[q * 4] * inv, v[q * 4 + 1] * inv,
                         v[q * 4 + 2] * inv, v[q * 4 + 3] * inv);
}

// ---------------- host ----------------
extern "C" void kernel_launch(void* const* d_in, const int* in_sizes, int n_in,
                              void* d_out, int out_size, void* d_ws, size_t ws_size,
                              hipStream_t stream) {
  const float* X    = (const float*)d_in[0];
  const int*   esrc = (const int*)d_in[1];
  const int*   edst = (const int*)d_in[2];
  const float* ew   = (const float*)d_in[3];
  const float* W1   = (const float*)d_in[4];
  const float* W2   = (const float*)d_in[5];
  float* out = (float*)d_out;

  // JAX: key = random.key(42); kd1, kd2 = random.split(key)  (partitionable)
  uint32_t kd1_0, kd1_1, kd2_0, kd2_1;
  tf2x32_full(0u, 42u, 0u, 0u, &kd1_0, &kd1_1);
  tf2x32_full(0u, 42u, 0u, 1u, &kd2_0, &kd2_1);

  const int nb_nodes = (N_NODES + 255) / 256;       // 391 (fallback kernels)

  // workspace: ep | H1 | H2d | mask1 | gcur
  const size_t sz_ep  = (size_t)NBUK * CAP * sizeof(int2);          // 29.6 MB
  const size_t sz_H1  = (size_t)N_NODES * HIDDEN * sizeof(float);   // 6.4 MB
  const size_t sz_H2d = sz_H1;                                      // 6.4 MB
  const size_t sz_mk  = (size_t)NW_MASK * sizeof(uint32_t);         // 6.4 MB
  const size_t sz_cur = (size_t)NBUK * sizeof(int);
  const size_t need = sz_ep + sz_H1 + sz_H2d + sz_mk + sz_cur;      // ~48.9 MB

  char* p = (char*)d_ws;
  int2* ep = (int2*)p;       p += sz_ep;
  float* H1 = (float*)p;     p += sz_H1;
  float* H2d = (float*)p;    p += sz_H2d;
  uint32_t* mask1 = (uint32_t*)p; p += sz_mk;
  int* gcur = (int*)p;

  if (ws_size >= need) {
    hipMemsetAsync(gcur, 0, sz_cur, stream);
    mask_gen<<<NB_MSK, 256, 0, stream>>>(mask1, kd1_0, kd1_1);
    bin_gemm1_fused<<<NB_BIN + NB_G1, 256, 0, stream>>>(
        X, W1, mask1, H1, esrc, edst, ew, gcur, ep);
    bucket_gather1<<<NBUK, 256, 0, stream>>>(gcur, ep, H1, H2d, kd2_0, kd2_1);
    bucket_gather2<<<NBUK, 256, 0, stream>>>(gcur, ep, H2d, W2, out);
  } else {
    // fallback: atomic path (25.6 MB)
    float* fH1 = (float*)d_ws;
    float* fH2 = fH1 + (size_t)N_NODES * HIDDEN;
    float* fH3 = fH2 + (size_t)N_NODES * HIDDEN;
    hipMemsetAsync(fH2, 0, (size_t)N_NODES * HIDDEN * sizeof(float), stream);
    hipMemsetAsync(out, 0, (size_t)out_size * sizeof(float), stream);
    gemm1_dropout_fb<<<nb_nodes, 256, 0, stream>>>(X, W1, fH1, kd1_0, kd1_1);
    spmm1_atomic<<<(N_EDGES * 4) / 256, 256, 0, stream>>>(esrc, edst, ew, fH1, fH2);
    gemm2_dropout<<<nb_nodes, 256, 0, stream>>>(fH2, W2, fH3, kd2_0, kd2_1);
    spmm2_atomic<<<(N_EDGES * 8) / 256, 256, 0, stream>>>(esrc, edst, ew, fH3, out);
    softmax_rows<<<nb_nodes, 256, 0, stream>>>(out);
  }
}

// Round 13
// 322.710 us; speedup vs baseline: 1.1694x; 1.0987x over previous
//
#include <hip/hip_runtime.h>
#include <stdint.h>
#include <stddef.h>

#define N_NODES   100000
#define N_EDGES   3200000
#define F_IN      512
#define HIDDEN    16
#define N_CLASSES 32

#define BSHIFT 6                        // 64 nodes per bucket
#define NBUK   ((N_NODES + 63) >> 6)    // 1563
#define CAP    2368                     // mean 2048, sigma ~45 -> +7 sigma
#define TILE   8192                     // edges per binning block
#define NB_BIN ((N_EDGES + TILE - 1) / TILE)      // 391
#define NW_MASK ((N_NODES * F_IN) / 32)           // 1,600,000 mask words
#define NB_MSK (NW_MASK / 256)                    // 6250
#define NB_G1  ((N_NODES + 63) / 64)              // 1563 (64 nodes/block)

// ---------------- Threefry-2x32, JAX-compatible (20 rounds) ----------------
__host__ __device__ __forceinline__ uint32_t rotl32(uint32_t x, int r) {
#ifdef __HIP_DEVICE_COMPILE__
  return __builtin_amdgcn_alignbit(x, x, (uint32_t)(32 - r));  // 1 op
#else
  return (x << r) | (x >> (32 - r));
#endif
}

__host__ __device__ __forceinline__ void tf2x32_full(uint32_t k0, uint32_t k1,
                                                     uint32_t x0, uint32_t x1,
                                                     uint32_t* o0, uint32_t* o1) {
  const uint32_t k2 = k0 ^ k1 ^ 0x1BD11BDAu;
  x0 += k0; x1 += k1;
#define TF_R(r) { x0 += x1; x1 = rotl32(x1, (r)); x1 ^= x0; }
  TF_R(13) TF_R(15) TF_R(26) TF_R(6)   x0 += k1; x1 += k2 + 1u;
  TF_R(17) TF_R(29) TF_R(16) TF_R(24)  x0 += k2; x1 += k0 + 2u;
  TF_R(13) TF_R(15) TF_R(26) TF_R(6)   x0 += k0; x1 += k1 + 3u;
  TF_R(17) TF_R(29) TF_R(16) TF_R(24)  x0 += k1; x1 += k2 + 4u;
  TF_R(13) TF_R(15) TF_R(26) TF_R(6)   x0 += k2; x1 += k0 + 5u;
#undef TF_R
  *o0 = x0; *o1 = x1;
}

// JAX partitionable random_bits(32): bits = out0 ^ out1 of tf(key; 0, idx).
// keep ⟺ uniform < 0.5 ⟺ MSB(bits)==0.
__device__ __forceinline__ bool keep_bit(uint32_t k0, uint32_t k1, uint32_t ctr) {
  uint32_t o0, o1;
  tf2x32_full(k0, k1, 0u, ctr, &o0, &o1);
  return (int32_t)(o0 ^ o1) >= 0;
}

// ---------------- k1: [0..NB_BIN) bin_edges | [NB_BIN..) dropout1 mask gen ----
// r10 structure: bin (memory/atomic-bound) overlaps mask threefry (VALU-bound).
// mask word m covers elements m*32..m*32+31 (LSB-first), element = node*512+f.
__launch_bounds__(256)
__global__ void bin_mask_fused(const int* __restrict__ src, const int* __restrict__ dst,
                               const float* __restrict__ w, int* __restrict__ gcur,
                               int2* __restrict__ ep, uint32_t* __restrict__ mask1,
                               uint32_t kd0, uint32_t kd1) {
  __shared__ int lh[NBUK];   // hist, then local cursor (bin path only)
  __shared__ int gb[NBUK];   // per-tile global range base
  const int tid = threadIdx.x;

  if (blockIdx.x < NB_BIN) {
    // ================= bin_edges path =================
    const int base = blockIdx.x * TILE;
    const int n = min(TILE, N_EDGES - base);

    for (int i = tid; i < NBUK; i += 256) lh[i] = 0;
    __syncthreads();

    for (int i = tid; i < n; i += 256)
      atomicAdd(&lh[dst[base + i] >> BSHIFT], 1);
    __syncthreads();

    for (int b = tid; b < NBUK; b += 256) {
      const int h = lh[b];
      gb[b] = h ? atomicAdd(&gcur[b], h) : 0;
      lh[b] = 0;  // owned by exactly one thread here; reuse as cursor
    }
    __syncthreads();

    for (int i = tid; i < n; i += 256) {
      const int e = base + i;
      const int d = dst[e];
      const int b = d >> BSHIFT;
      const int pos = gb[b] + atomicAdd(&lh[b], 1);
      if (pos < CAP)
        ep[(size_t)b * CAP + pos] =
            make_int2(src[e] | ((d & 63) << 17), __float_as_int(w[e]));
    }
    return;
  }

  // ================= mask1 generation =================
  const int mt = (blockIdx.x - NB_BIN) * 256 + tid;   // word index
  if (mt < NW_MASK) {
    const uint32_t base = (uint32_t)mt * 32u;
    uint32_t word = 0u;
#pragma unroll
    for (int j = 0; j < 32; j++) {
      uint32_t o0, o1;
      tf2x32_full(kd0, kd1, 0u, base + (uint32_t)j, &o0, &o1);
      word |= ((~(o0 ^ o1)) >> 31) << j;   // MSB==0 -> keep
    }
    mask1[mt] = word;
  }
}

// ---------------- k2: gemm1 via precomputed mask: dropout(X) @ W1 -> H1 ----
// r10's proven body: 4 threads/node (K-split over f), 64 nodes/block,
// W1 in LDS with 2-bit XOR chunk swizzle (conflict-free b128 across p).
// Mask words loaded as uint4 per 4-iteration group (static component refs).
__launch_bounds__(256)
__global__ void gemm1_mask(const float* __restrict__ X,
                           const float* __restrict__ W1,
                           const uint32_t* __restrict__ mask1,
                           float* __restrict__ H1) {
  __shared__ __align__(16) float W1s[F_IN * HIDDEN];  // 32 KB
  const int tid = threadIdx.x;
  for (int i = tid; i < (F_IN * HIDDEN) / 4; i += 256) {
    const int f = i >> 2, m = i & 3;
    ((float4*)W1s)[f * 4 + (m ^ ((f >> 2) & 3))] = ((const float4*)W1)[i];
  }
  __syncthreads();

  const int p = tid & 3;                       // K-quarter
  const int node = blockIdx.x * 64 + (tid >> 2);
  if (node >= N_NODES) return;                 // no barriers after this point

  float acc[16];
#pragma unroll
  for (int j = 0; j < 16; j++) acc[j] = 0.0f;

  const float4* Xrow4 = (const float4*)(X + (size_t)node * F_IN);
  const uint4* M4 = (const uint4*)(mask1 + (size_t)node * 16);
  const int sh0 = p << 2;          // low half (even sub-iter)
  const int sh1 = 16 + (p << 2);   // high half

#define PROC(IT2, MWORD)                                              \
  {                                                                   \
    const uint32_t mword = (MWORD);                                   \
    const float4 xv0 = Xrow4[(IT2) * 8 + p];                          \
    const float4 xv1 = Xrow4[(IT2) * 8 + 4 + p];                      \
    const float xs0[4] = {xv0.x, xv0.y, xv0.z, xv0.w};                \
    const float xs1[4] = {xv1.x, xv1.y, xv1.z, xv1.w};                \
    _Pragma("unroll")                                                 \
    for (int e = 0; e < 4; e++) {                                     \
      const float xd = ((mword >> (sh0 + e)) & 1u) ? xs0[e] + xs0[e]  \
                                                   : 0.0f;            \
      const int f = (IT2) * 32 + p * 4 + e;                           \
      const float4* row = (const float4*)&W1s[f * 16];                \
      _Pragma("unroll")                                               \
      for (int q = 0; q < 4; q++) {                                   \
        const float4 wv = row[q ^ p];                                 \
        acc[q * 4 + 0] += xd * wv.x;                                  \
        acc[q * 4 + 1] += xd * wv.y;                                  \
        acc[q * 4 + 2] += xd * wv.z;                                  \
        acc[q * 4 + 3] += xd * wv.w;                                  \
      }                                                               \
    }                                                                 \
    _Pragma("unroll")                                                 \
    for (int e = 0; e < 4; e++) {                                     \
      const float xd = ((mword >> (sh1 + e)) & 1u) ? xs1[e] + xs1[e]  \
                                                   : 0.0f;            \
      const int f = (IT2) * 32 + 16 + p * 4 + e;                      \
      const float4* row = (const float4*)&W1s[f * 16];                \
      _Pragma("unroll")                                               \
      for (int q = 0; q < 4; q++) {                                   \
        const float4 wv = row[q ^ p];                                 \
        acc[q * 4 + 0] += xd * wv.x;                                  \
        acc[q * 4 + 1] += xd * wv.y;                                  \
        acc[q * 4 + 2] += xd * wv.z;                                  \
        acc[q * 4 + 3] += xd * wv.w;                                  \
      }                                                               \
    }                                                                 \
  }

  for (int g = 0; g < 4; ++g) {        // 4 groups x 4 it2 = 16
    const uint4 mw4 = M4[g];
    const int i0 = g * 4;
    PROC(i0 + 0, mw4.x)
    PROC(i0 + 1, mw4.y)
    PROC(i0 + 2, mw4.z)
    PROC(i0 + 3, mw4.w)
  }
#undef PROC

  // cross-p reduce (4 lanes/node); value-selects keep reg indices static
  float a2[8];
#pragma unroll
  for (int k = 0; k < 8; k++) {
    const float keep = (p & 2) ? acc[8 + k] : acc[k];
    const float send = (p & 2) ? acc[k]     : acc[8 + k];
    a2[k] = keep + __shfl_xor(send, 2);
  }
  float r0, r1, r2, r3;
  {
    const float k0v = (p & 1) ? a2[4] : a2[0];
    const float s0v = (p & 1) ? a2[0] : a2[4];
    r0 = k0v + __shfl_xor(s0v, 1);
    const float k1v = (p & 1) ? a2[5] : a2[1];
    const float s1v = (p & 1) ? a2[1] : a2[5];
    r1 = k1v + __shfl_xor(s1v, 1);
    const float k2v = (p & 1) ? a2[6] : a2[2];
    const float s2v = (p & 1) ? a2[2] : a2[6];
    r2 = k2v + __shfl_xor(s2v, 1);
    const float k3v = (p & 1) ? a2[7] : a2[3];
    const float s3v = (p & 1) ? a2[3] : a2[7];
    r3 = k3v + __shfl_xor(s3v, 1);
  }
  *(float4*)(H1 + (size_t)node * HIDDEN + p * 4) = make_float4(r0, r1, r2, r3);
}

// ---------------- gather1: H2d = dropout2(relu(A @ H1)); also writes the
// node-sorted records back to ep and per-bucket lex/lh so gather2 skips the
// sort entirely.
__launch_bounds__(256)
__global__ void bucket_gather1(const int* __restrict__ gcur, int2* __restrict__ ep,
                               const float* __restrict__ H1, float* __restrict__ H2d,
                               int* __restrict__ lexA, int* __restrict__ lhA,
                               uint32_t k0, uint32_t k1) {
  __shared__ int2 B[CAP];                // 18.5 KB
  __shared__ int lh[64], lex[64], lcur[64];
  const int tid = threadIdx.x;
  const int b = blockIdx.x;

  if (tid < 64) lh[tid] = 0;
  __syncthreads();

  const int c = min(gcur[b], CAP);
  int2* ebase = ep + (size_t)b * CAP;

  for (int k = tid; k < c; k += 256)
    atomicAdd(&lh[(ebase[k].x >> 17) & 63], 1);
  __syncthreads();

  if (tid < 64) {  // wave 0: 64-lane exclusive scan
    const int v = lh[tid];
    int s = v;
    for (int off = 1; off < 64; off <<= 1) {
      const int t = __shfl_up(s, off);
      if (tid >= off) s += t;
    }
    lex[tid] = s - v;
    lcur[tid] = s - v;
  }
  __syncthreads();

  for (int k = tid; k < c; k += 256) {
    const int2 r = ebase[k];
    const int p = atomicAdd(&lcur[(r.x >> 17) & 63], 1);
    B[p] = r;
  }
  __syncthreads();

  // write back sorted records + boundaries for gather2 (fire-and-forget)
  for (int k = tid; k < c; k += 256) ebase[k] = B[k];
  if (tid < 64) {
    lexA[b * 64 + tid] = lex[tid];
    lhA[b * 64 + tid] = lh[tid];
  }

  const int lane = tid & 63, wid = tid >> 6;
  const int ei = lane >> 4, f = lane & 15;
  for (int ln = wid; ln < 64; ln += 4) {
    const int ng = (b << BSHIFT) + ln;
    if (ng >= N_NODES) break;
    const int beg = lex[ln], cnt = lh[ln];
    float acc = 0.0f;
    for (int k = beg + ei; k < beg + cnt; k += 4) {
      const int2 r = B[k];
      acc += __int_as_float(r.y) * H1[(size_t)(r.x & 0x1FFFF) * HIDDEN + f];
    }
    acc += __shfl_xor(acc, 16);
    acc += __shfl_xor(acc, 32);
    // relu + dropout2 (mask over [N,16], idx = ng*16 + f)
    float v = fmaxf(acc, 0.0f);
    v = keep_bit(k0, k1, (uint32_t)ng * HIDDEN + (uint32_t)f) ? v * 2.0f : 0.0f;
    if (lane < 16) H2d[(size_t)ng * HIDDEN + f] = v;
  }
}

// ---------------- gather2: out = softmax((A @ H2d) @ W2) [N,32] ----------------
// No sort: records already node-sorted in ep; boundaries in lexA/lhA.
// Records read directly from global (sequential, wave-broadcast to 16 lanes).
__launch_bounds__(256)
__global__ void bucket_gather2(const int* __restrict__ lexA, const int* __restrict__ lhA,
                               const int2* __restrict__ ep,
                               const float* __restrict__ H2d, const float* __restrict__ W2,
                               float* __restrict__ O) {
  __shared__ float W2s[HIDDEN][N_CLASSES];  // 2 KB
  __shared__ int lex[64], lh[64];
  const int tid = threadIdx.x;
  const int b = blockIdx.x;

  for (int i = tid; i < HIDDEN * N_CLASSES; i += 256) ((float*)W2s)[i] = W2[i];
  if (tid < 64) {
    lex[tid] = lexA[b * 64 + tid];
    lh[tid] = lhA[b * 64 + tid];
  }
  __syncthreads();

  const int2* base = ep + (size_t)b * CAP;
  const int lane = tid & 63, wid = tid >> 6;
  const int ei = lane >> 4, f = lane & 15;
  const int cl = lane & 31;
  for (int ln = wid; ln < 64; ln += 4) {
    const int ng = (b << BSHIFT) + ln;
    if (ng >= N_NODES) break;
    const int beg = lex[ln], cnt = lh[ln];
    float acc = 0.0f;
    for (int k = beg + ei; k < beg + cnt; k += 4) {
      const int2 r = base[k];
      acc += __int_as_float(r.y) * H2d[(size_t)(r.x & 0x1FFFF) * HIDDEN + f];
    }
    acc += __shfl_xor(acc, 16);
    acc += __shfl_xor(acc, 32);   // every lane now holds G2[ng][lane&15]
    // logits: c = lane&31 ; lg = sum_f G2[f] * W2[f][c]
    float lg = 0.0f;
#pragma unroll
    for (int fq = 0; fq < HIDDEN; fq++)
      lg += __shfl(acc, fq) * W2s[fq][cl];
    // softmax across the 32-lane group
    float m = lg;
#pragma unroll
    for (int off = 16; off >= 1; off >>= 1) m = fmaxf(m, __shfl_xor(m, off));
    const float ex = __expf(lg - m);
    float ss = ex;
#pragma unroll
    for (int off = 16; off >= 1; off >>= 1) ss += __shfl_xor(ss, off);
    if (lane < 32) O[(size_t)ng * N_CLASSES + cl] = ex / ss;
  }
}

// ================= fallback atomic path (small ws) =================
__launch_bounds__(256)
__global__ void gemm1_dropout_fb(const float* __restrict__ X,
                                 const float* __restrict__ W1,
                                 float* __restrict__ H1,
                                 uint32_t kd0, uint32_t kd1) {
  __shared__ float W1s[F_IN][HIDDEN];
  const int tid = threadIdx.x;
  for (int i = tid; i < (F_IN * HIDDEN) / 4; i += 256)
    ((float4*)W1s)[i] = ((const float4*)W1)[i];
  __syncthreads();
  const int n = blockIdx.x * 256 + tid;
  if (n >= N_NODES) return;
  float acc[HIDDEN];
#pragma unroll
  for (int j = 0; j < HIDDEN; j++) acc[j] = 0.0f;
  const float4* Xrow = (const float4*)(X + (size_t)n * F_IN);
  const uint32_t jbase = (uint32_t)n * F_IN;
  for (int cc = 0; cc < F_IN / 4; cc++) {
    float4 xv = Xrow[cc];
    float xs[4] = {xv.x, xv.y, xv.z, xv.w};
#pragma unroll
    for (int e = 0; e < 4; e++) {
      const int f = cc * 4 + e;
      const float x = keep_bit(kd0, kd1, jbase + (uint32_t)f) ? xs[e] * 2.0f : 0.0f;
      const float* wr = W1s[f];
#pragma unroll
      for (int j = 0; j < HIDDEN; j++) acc[j] += x * wr[j];
    }
  }
  float4* out = (float4*)(H1 + (size_t)n * HIDDEN);
#pragma unroll
  for (int q = 0; q < HIDDEN / 4; q++)
    out[q] = make_float4(acc[q * 4], acc[q * 4 + 1], acc[q * 4 + 2], acc[q * 4 + 3]);
}

__launch_bounds__(256)
__global__ void spmm1_atomic(const int* __restrict__ src, const int* __restrict__ dst,
                             const float* __restrict__ w, const float* __restrict__ H1,
                             float* __restrict__ H2) {
  const long long t = (long long)blockIdx.x * 256 + threadIdx.x;
  if (t >= (long long)N_EDGES * 4) return;
  const int e = (int)(t >> 2);
  const int q = (int)(t & 3);
  const float we = w[e];
  const float4 h = ((const float4*)(H1 + (size_t)src[e] * HIDDEN))[q];
  float* o = H2 + (size_t)dst[e] * HIDDEN + q * 4;
  unsafeAtomicAdd(o + 0, we * h.x);
  unsafeAtomicAdd(o + 1, we * h.y);
  unsafeAtomicAdd(o + 2, we * h.z);
  unsafeAtomicAdd(o + 3, we * h.w);
}

__launch_bounds__(256)
__global__ void gemm2_dropout(const float* __restrict__ H2,
                              const float* __restrict__ W2,
                              float* __restrict__ H3,
                              uint32_t kd0, uint32_t kd1) {
  __shared__ float W2s[HIDDEN][N_CLASSES];
  const int tid = threadIdx.x;
  for (int i = tid; i < (HIDDEN * N_CLASSES) / 4; i += 256)
    ((float4*)W2s)[i] = ((const float4*)W2)[i];
  __syncthreads();
  const int n = blockIdx.x * 256 + tid;
  if (n >= N_NODES) return;
  float acc[N_CLASSES];
#pragma unroll
  for (int j = 0; j < N_CLASSES; j++) acc[j] = 0.0f;
  const float4* hrow = (const float4*)(H2 + (size_t)n * HIDDEN);
  const uint32_t jbase = (uint32_t)n * HIDDEN;
#pragma unroll
  for (int qq = 0; qq < HIDDEN / 4; qq++) {
    float4 hv = hrow[qq];
    float hs[4] = {hv.x, hv.y, hv.z, hv.w};
#pragma unroll
    for (int e = 0; e < 4; e++) {
      const int cc = qq * 4 + e;
      float h = fmaxf(hs[e], 0.0f);
      h = keep_bit(kd0, kd1, jbase + (uint32_t)cc) ? h * 2.0f : 0.0f;
      const float* wr = W2s[cc];
#pragma unroll
      for (int j = 0; j < N_CLASSES; j++) acc[j] += h * wr[j];
    }
  }
  float4* out = (float4*)(H3 + (size_t)n * N_CLASSES);
#pragma unroll
  for (int q = 0; q < N_CLASSES / 4; q++)
    out[q] = make_float4(acc[q * 4], acc[q * 4 + 1], acc[q * 4 + 2], acc[q * 4 + 3]);
}

__launch_bounds__(256)
__global__ void spmm2_atomic(const int* __restrict__ src, const int* __restrict__ dst,
                             const float* __restrict__ w, const float* __restrict__ H3,
                             float* __restrict__ O) {
  const long long t = (long long)blockIdx.x * 256 + threadIdx.x;
  if (t >= (long long)N_EDGES * 8) return;
  const int e = (int)(t >> 3);
  const int q = (int)(t & 7);
  const float we = w[e];
  const float4 h = ((const float4*)(H3 + (size_t)src[e] * N_CLASSES))[q];
  float* o = O + (size_t)dst[e] * N_CLASSES + q * 4;
  unsafeAtomicAdd(o + 0, we * h.x);
  unsafeAtomicAdd(o + 1, we * h.y);
  unsafeAtomicAdd(o + 2, we * h.z);
  unsafeAtomicAdd(o + 3, we * h.w);
}

__launch_bounds__(256)
__global__ void softmax_rows(float* __restrict__ O) {
  const int n = blockIdx.x * 256 + threadIdx.x;
  if (n >= N_NODES) return;
  float4* row = (float4*)(O + (size_t)n * N_CLASSES);
  float v[N_CLASSES];
#pragma unroll
  for (int q = 0; q < N_CLASSES / 4; q++) {
    float4 t = row[q];
    v[q * 4 + 0] = t.x; v[q * 4 + 1] = t.y; v[q * 4 + 2] = t.z; v[q * 4 + 3] = t.w;
  }
  float m = v[0];
#pragma unroll
  for (int j = 1; j < N_CLASSES; j++) m = fmaxf(m, v[j]);
  float s = 0.0f;
#pragma unroll
  for (int j = 0; j < N_CLASSES; j++) { v[j] = __expf(v[j] - m); s += v[j]; }
  const float inv = 1.0f / s;
#pragma unroll
  for (int q = 0; q < N_CLASSES / 4; q++)
    row[q] = make_float4(v[q * 4] * inv, v[q * 4 + 1] * inv,
                         v[q * 4 + 2] * inv, v[q * 4 + 3] * inv);
}

// ---------------- host ----------------
extern "C" void kernel_launch(void* const* d_in, const int* in_sizes, int n_in,
                              void* d_out, int out_size, void* d_ws, size_t ws_size,
                              hipStream_t stream) {
  const float* X    = (const float*)d_in[0];
  const int*   esrc = (const int*)d_in[1];
  const int*   edst = (const int*)d_in[2];
  const float* ew   = (const float*)d_in[3];
  const float* W1   = (const float*)d_in[4];
  const float* W2   = (const float*)d_in[5];
  float* out = (float*)d_out;

  // JAX: key = random.key(42); kd1, kd2 = random.split(key)  (partitionable)
  uint32_t kd1_0, kd1_1, kd2_0, kd2_1;
  tf2x32_full(0u, 42u, 0u, 0u, &kd1_0, &kd1_1);
  tf2x32_full(0u, 42u, 0u, 1u, &kd2_0, &kd2_1);

  const int nb_nodes = (N_NODES + 255) / 256;       // 391 (fallback kernels)

  // workspace: ep | H1 | H2d | mask1 | gcur | lexA | lhA
  const size_t sz_ep  = (size_t)NBUK * CAP * sizeof(int2);          // 29.6 MB
  const size_t sz_H1  = (size_t)N_NODES * HIDDEN * sizeof(float);   // 6.4 MB
  const size_t sz_H2d = sz_H1;                                      // 6.4 MB
  const size_t sz_mk  = (size_t)NW_MASK * sizeof(uint32_t);         // 6.4 MB
  const size_t sz_cur = (size_t)NBUK * sizeof(int);
  const size_t sz_lex = (size_t)NBUK * 64 * sizeof(int);            // 400 KB
  const size_t need = sz_ep + sz_H1 + sz_H2d + sz_mk + sz_cur + 2 * sz_lex;

  char* p = (char*)d_ws;
  int2* ep = (int2*)p;       p += sz_ep;
  float* H1 = (float*)p;     p += sz_H1;
  float* H2d = (float*)p;    p += sz_H2d;
  uint32_t* mask1 = (uint32_t*)p; p += sz_mk;
  int* gcur = (int*)p;       p += sz_cur;
  int* lexA = (int*)p;       p += sz_lex;
  int* lhA = (int*)p;

  if (ws_size >= need) {
    hipMemsetAsync(gcur, 0, sz_cur, stream);
    bin_mask_fused<<<NB_BIN + NB_MSK, 256, 0, stream>>>(
        esrc, edst, ew, gcur, ep, mask1, kd1_0, kd1_1);
    gemm1_mask<<<NB_G1, 256, 0, stream>>>(X, W1, mask1, H1);
    bucket_gather1<<<NBUK, 256, 0, stream>>>(gcur, ep, H1, H2d, lexA, lhA,
                                             kd2_0, kd2_1);
    bucket_gather2<<<NBUK, 256, 0, stream>>>(lexA, lhA, ep, H2d, W2, out);
  } else {
    // fallback: atomic path (25.6 MB)
    float* fH1 = (float*)d_ws;
    float* fH2 = fH1 + (size_t)N_NODES * HIDDEN;
    float* fH3 = fH2 + (size_t)N_NODES * HIDDEN;
    hipMemsetAsync(fH2, 0, (size_t)N_NODES * HIDDEN * sizeof(float), stream);
    hipMemsetAsync(out, 0, (size_t)out_size * sizeof(float), stream);
    gemm1_dropout_fb<<<nb_nodes, 256, 0, stream>>>(X, W1, fH1, kd1_0, kd1_1);
    spmm1_atomic<<<(N_EDGES * 4) / 256, 256, 0, stream>>>(esrc, edst, ew, fH1, fH2);
    gemm2_dropout<<<nb_nodes, 256, 0, stream>>>(fH2, W2, fH3, kd2_0, kd2_1);
    spmm2_atomic<<<(N_EDGES * 8) / 256, 256, 0, stream>>>(esrc, edst, ew, fH3, out);
    softmax_rows<<<nb_nodes, 256, 0, stream>>>(out);
  }
}

// Round 14
// 273.910 us; speedup vs baseline: 1.3777x; 1.1782x over previous
//
#include <hip/hip_runtime.h>
#include <stdint.h>
#include <stddef.h>

#define N_NODES   100000
#define N_EDGES   3200000
#define F_IN      512
#define HIDDEN    16
#define N_CLASSES 32

#define BSHIFT 6                        // 64 nodes per bucket
#define NBUK   ((N_NODES + 63) >> 6)    // 1563
#define CAP    2368                     // mean 2048, sigma ~45 -> +7 sigma
#define TILE   8192                     // edges per binning block
#define NB_BIN ((N_EDGES + TILE - 1) / TILE)      // 391
#define NW_MASK ((N_NODES * F_IN) / 32)           // 1,600,000 mask words
#define NB_MSK (NW_MASK / 256)                    // 6250
#define NB_G1  ((N_NODES + 63) / 64)              // 1563 (64 nodes/block)

// ---------------- Threefry-2x32, JAX-compatible (20 rounds) ----------------
__host__ __device__ __forceinline__ uint32_t rotl32(uint32_t x, int r) {
#ifdef __HIP_DEVICE_COMPILE__
  return __builtin_amdgcn_alignbit(x, x, (uint32_t)(32 - r));  // 1 op
#else
  return (x << r) | (x >> (32 - r));
#endif
}

__host__ __device__ __forceinline__ void tf2x32_full(uint32_t k0, uint32_t k1,
                                                     uint32_t x0, uint32_t x1,
                                                     uint32_t* o0, uint32_t* o1) {
  const uint32_t k2 = k0 ^ k1 ^ 0x1BD11BDAu;
  x0 += k0; x1 += k1;
#define TF_R(r) { x0 += x1; x1 = rotl32(x1, (r)); x1 ^= x0; }
  TF_R(13) TF_R(15) TF_R(26) TF_R(6)   x0 += k1; x1 += k2 + 1u;
  TF_R(17) TF_R(29) TF_R(16) TF_R(24)  x0 += k2; x1 += k0 + 2u;
  TF_R(13) TF_R(15) TF_R(26) TF_R(6)   x0 += k0; x1 += k1 + 3u;
  TF_R(17) TF_R(29) TF_R(16) TF_R(24)  x0 += k1; x1 += k2 + 4u;
  TF_R(13) TF_R(15) TF_R(26) TF_R(6)   x0 += k2; x1 += k0 + 5u;
#undef TF_R
  *o0 = x0; *o1 = x1;
}

// JAX partitionable random_bits(32): bits = out0 ^ out1 of tf(key; 0, idx).
// keep ⟺ uniform < 0.5 ⟺ MSB(bits)==0.
__device__ __forceinline__ bool keep_bit(uint32_t k0, uint32_t k1, uint32_t ctr) {
  uint32_t o0, o1;
  tf2x32_full(k0, k1, 0u, ctr, &o0, &o1);
  return (int32_t)(o0 ^ o1) >= 0;
}

// ---------------- k1: [0..NB_BIN) bin_edges | [NB_BIN..) dropout1 mask gen ----
// r10 structure: bin (memory/atomic-bound) overlaps mask threefry (VALU-bound).
// mask word m covers elements m*32..m*32+31 (LSB-first), element = node*512+f.
__launch_bounds__(256)
__global__ void bin_mask_fused(const int* __restrict__ src, const int* __restrict__ dst,
                               const float* __restrict__ w, int* __restrict__ gcur,
                               int2* __restrict__ ep, uint32_t* __restrict__ mask1,
                               uint32_t kd0, uint32_t kd1) {
  __shared__ int lh[NBUK];   // hist, then local cursor (bin path only)
  __shared__ int gb[NBUK];   // per-tile global range base
  const int tid = threadIdx.x;

  if (blockIdx.x < NB_BIN) {
    // ================= bin_edges path =================
    const int base = blockIdx.x * TILE;
    const int n = min(TILE, N_EDGES - base);

    for (int i = tid; i < NBUK; i += 256) lh[i] = 0;
    __syncthreads();

    for (int i = tid; i < n; i += 256)
      atomicAdd(&lh[dst[base + i] >> BSHIFT], 1);
    __syncthreads();

    for (int b = tid; b < NBUK; b += 256) {
      const int h = lh[b];
      gb[b] = h ? atomicAdd(&gcur[b], h) : 0;
      lh[b] = 0;  // owned by exactly one thread here; reuse as cursor
    }
    __syncthreads();

    for (int i = tid; i < n; i += 256) {
      const int e = base + i;
      const int d = dst[e];
      const int b = d >> BSHIFT;
      const int pos = gb[b] + atomicAdd(&lh[b], 1);
      if (pos < CAP)
        ep[(size_t)b * CAP + pos] =
            make_int2(src[e] | ((d & 63) << 17), __float_as_int(w[e]));
    }
    return;
  }

  // ================= mask1 generation =================
  const int mt = (blockIdx.x - NB_BIN) * 256 + tid;   // word index
  if (mt < NW_MASK) {
    const uint32_t base = (uint32_t)mt * 32u;
    uint32_t word = 0u;
#pragma unroll
    for (int j = 0; j < 32; j++) {
      uint32_t o0, o1;
      tf2x32_full(kd0, kd1, 0u, base + (uint32_t)j, &o0, &o1);
      word |= ((~(o0 ^ o1)) >> 31) << j;   // MSB==0 -> keep
    }
    mask1[mt] = word;
  }
}

// ---------------- k2: gemm1 via precomputed mask: dropout(X) @ W1 -> H1 ----
// r10's exact proven body: 4 threads/node (K-split over f = it*16+4p+e),
// 64 nodes/block, W1 in LDS with 2-bit XOR chunk swizzle.
// Dropout = bit test on mask1 (word = node*16 + (it>>1), bit = (it&1)*16+4p+e).
__launch_bounds__(256)
__global__ void gemm1_mask(const float* __restrict__ X,
                           const float* __restrict__ W1,
                           const uint32_t* __restrict__ mask1,
                           float* __restrict__ H1) {
  __shared__ float W1s[F_IN * HIDDEN];  // 32 KB; chunk m of row f at pos m^((f>>2)&3)
  const int tid = threadIdx.x;
  for (int i = tid; i < (F_IN * HIDDEN) / 4; i += 256) {
    const int f = i >> 2, m = i & 3;
    ((float4*)W1s)[f * 4 + (m ^ ((f >> 2) & 3))] = ((const float4*)W1)[i];
  }
  __syncthreads();

  const int p = tid & 3;                       // K-quarter
  const int node = blockIdx.x * 64 + (tid >> 2);
  if (node >= N_NODES) return;                 // no barriers after this point

  float acc[16];
#pragma unroll
  for (int j = 0; j < 16; j++) acc[j] = 0.0f;

  const float4* Xrow4 = (const float4*)(X + (size_t)node * F_IN);
  const uint32_t* Mrow = mask1 + (size_t)node * 16;
  const int sh0 = p << 2;          // nibble shift, low half (it even)
  const int sh1 = 16 + (p << 2);   // high half (it odd)

  for (int it2 = 0; it2 < 16; ++it2) {   // it = 2*it2, 2*it2+1
    const uint32_t mword = Mrow[it2];
    const float4 xv0 = Xrow4[it2 * 8 + p];
    const float4 xv1 = Xrow4[it2 * 8 + 4 + p];
    const uint32_t nib0 = mword >> sh0;
    const uint32_t nib1 = mword >> sh1;
    const float xs0[4] = {xv0.x, xv0.y, xv0.z, xv0.w};
    const float xs1[4] = {xv1.x, xv1.y, xv1.z, xv1.w};

#pragma unroll
    for (int e = 0; e < 4; e++) {
      const float xd = (nib0 >> e) & 1u ? xs0[e] + xs0[e] : 0.0f;
      const int f = it2 * 32 + p * 4 + e;
      const float4* row = (const float4*)&W1s[f * 16];
#pragma unroll
      for (int q = 0; q < 4; q++) {
        const float4 wv = row[q ^ p];
        acc[q * 4 + 0] += xd * wv.x;
        acc[q * 4 + 1] += xd * wv.y;
        acc[q * 4 + 2] += xd * wv.z;
        acc[q * 4 + 3] += xd * wv.w;
      }
    }
#pragma unroll
    for (int e = 0; e < 4; e++) {
      const float xd = (nib1 >> e) & 1u ? xs1[e] + xs1[e] : 0.0f;
      const int f = it2 * 32 + 16 + p * 4 + e;
      const float4* row = (const float4*)&W1s[f * 16];
#pragma unroll
      for (int q = 0; q < 4; q++) {
        const float4 wv = row[q ^ p];
        acc[q * 4 + 0] += xd * wv.x;
        acc[q * 4 + 1] += xd * wv.y;
        acc[q * 4 + 2] += xd * wv.z;
        acc[q * 4 + 3] += xd * wv.w;
      }
    }
  }

  // cross-p reduce (4 lanes per node); value-selects keep all reg indices static
  float a2[8];
#pragma unroll
  for (int k = 0; k < 8; k++) {
    const float keep = (p & 2) ? acc[8 + k] : acc[k];
    const float send = (p & 2) ? acc[k]     : acc[8 + k];
    a2[k] = keep + __shfl_xor(send, 2);
  }
  float r0, r1, r2, r3;
  {
    const float k0v = (p & 1) ? a2[4] : a2[0];
    const float s0v = (p & 1) ? a2[0] : a2[4];
    r0 = k0v + __shfl_xor(s0v, 1);
    const float k1v = (p & 1) ? a2[5] : a2[1];
    const float s1v = (p & 1) ? a2[1] : a2[5];
    r1 = k1v + __shfl_xor(s1v, 1);
    const float k2v = (p & 1) ? a2[6] : a2[2];
    const float s2v = (p & 1) ? a2[2] : a2[6];
    r2 = k2v + __shfl_xor(s2v, 1);
    const float k3v = (p & 1) ? a2[7] : a2[3];
    const float s3v = (p & 1) ? a2[3] : a2[7];
    r3 = k3v + __shfl_xor(s3v, 1);
  }
  *(float4*)(H1 + (size_t)node * HIDDEN + p * 4) = make_float4(r0, r1, r2, r3);
}

// ---------------- gather1: H2d = dropout2(relu(A @ H1)) [N,16] ----------------
// r10 body; edge loop unrolled 2x with dual accumulators (MLP: two independent
// record->gather chains in flight per lane).
__launch_bounds__(256)
__global__ void bucket_gather1(const int* __restrict__ gcur, const int2* __restrict__ ep,
                               const float* __restrict__ H1, float* __restrict__ H2d,
                               uint32_t k0, uint32_t k1) {
  __shared__ int2 B[CAP];                // 18.5 KB
  __shared__ int lh[64], lex[64], lcur[64];
  const int tid = threadIdx.x;
  const int b = blockIdx.x;

  if (tid < 64) lh[tid] = 0;
  __syncthreads();

  const int c = min(gcur[b], CAP);
  const int2* ebase = ep + (size_t)b * CAP;

  for (int k = tid; k < c; k += 256)
    atomicAdd(&lh[(ebase[k].x >> 17) & 63], 1);
  __syncthreads();

  if (tid < 64) {  // wave 0: 64-lane exclusive scan
    const int v = lh[tid];
    int s = v;
    for (int off = 1; off < 64; off <<= 1) {
      const int t = __shfl_up(s, off);
      if (tid >= off) s += t;
    }
    lex[tid] = s - v;
    lcur[tid] = s - v;
  }
  __syncthreads();

  for (int k = tid; k < c; k += 256) {
    const int2 r = ebase[k];
    const int p = atomicAdd(&lcur[(r.x >> 17) & 63], 1);
    B[p] = r;
  }
  __syncthreads();

  const int lane = tid & 63, wid = tid >> 6;
  const int ei = lane >> 4, f = lane & 15;
  for (int ln = wid; ln < 64; ln += 4) {
    const int ng = (b << BSHIFT) + ln;
    if (ng >= N_NODES) break;
    const int beg = lex[ln];
    const int end = beg + lh[ln];
    float acc = 0.0f, acc2 = 0.0f;
    int k = beg + ei;
    for (; k + 4 < end; k += 8) {   // 2 independent chains
      const int2 r0 = B[k];
      const int2 r1 = B[k + 4];
      acc  += __int_as_float(r0.y) * H1[(size_t)(r0.x & 0x1FFFF) * HIDDEN + f];
      acc2 += __int_as_float(r1.y) * H1[(size_t)(r1.x & 0x1FFFF) * HIDDEN + f];
    }
    if (k < end) {
      const int2 r0 = B[k];
      acc += __int_as_float(r0.y) * H1[(size_t)(r0.x & 0x1FFFF) * HIDDEN + f];
    }
    acc += acc2;
    acc += __shfl_xor(acc, 16);
    acc += __shfl_xor(acc, 32);
    // relu + dropout2 (mask over [N,16], idx = ng*16 + f)
    float v = fmaxf(acc, 0.0f);
    v = keep_bit(k0, k1, (uint32_t)ng * HIDDEN + (uint32_t)f) ? v * 2.0f : 0.0f;
    if (lane < 16) H2d[(size_t)ng * HIDDEN + f] = v;
  }
}

// ---------------- gather2: out = softmax((A @ H2d) @ W2) [N,32] ----------------
// r10 body (LDS sort retained); edge loop unrolled 2x with dual accumulators.
__launch_bounds__(256)
__global__ void bucket_gather2(const int* __restrict__ gcur, const int2* __restrict__ ep,
                               const float* __restrict__ H2d, const float* __restrict__ W2,
                               float* __restrict__ O) {
  __shared__ int2 B[CAP];
  __shared__ float W2s[HIDDEN][N_CLASSES];  // 2 KB
  __shared__ int lh[64], lex[64], lcur[64];
  const int tid = threadIdx.x;
  const int b = blockIdx.x;

  if (tid < 64) lh[tid] = 0;
  for (int i = tid; i < HIDDEN * N_CLASSES; i += 256) ((float*)W2s)[i] = W2[i];
  __syncthreads();

  const int c = min(gcur[b], CAP);
  const int2* ebase = ep + (size_t)b * CAP;

  for (int k = tid; k < c; k += 256)
    atomicAdd(&lh[(ebase[k].x >> 17) & 63], 1);
  __syncthreads();

  if (tid < 64) {
    const int v = lh[tid];
    int s = v;
    for (int off = 1; off < 64; off <<= 1) {
      const int t = __shfl_up(s, off);
      if (tid >= off) s += t;
    }
    lex[tid] = s - v;
    lcur[tid] = s - v;
  }
  __syncthreads();

  for (int k = tid; k < c; k += 256) {
    const int2 r = ebase[k];
    const int p = atomicAdd(&lcur[(r.x >> 17) & 63], 1);
    B[p] = r;
  }
  __syncthreads();

  const int lane = tid & 63, wid = tid >> 6;
  const int ei = lane >> 4, f = lane & 15;
  const int cl = lane & 31;
  for (int ln = wid; ln < 64; ln += 4) {
    const int ng = (b << BSHIFT) + ln;
    if (ng >= N_NODES) break;
    const int beg = lex[ln];
    const int end = beg + lh[ln];
    float acc = 0.0f, acc2 = 0.0f;
    int k = beg + ei;
    for (; k + 4 < end; k += 8) {   // 2 independent chains
      const int2 r0 = B[k];
      const int2 r1 = B[k + 4];
      acc  += __int_as_float(r0.y) * H2d[(size_t)(r0.x & 0x1FFFF) * HIDDEN + f];
      acc2 += __int_as_float(r1.y) * H2d[(size_t)(r1.x & 0x1FFFF) * HIDDEN + f];
    }
    if (k < end) {
      const int2 r0 = B[k];
      acc += __int_as_float(r0.y) * H2d[(size_t)(r0.x & 0x1FFFF) * HIDDEN + f];
    }
    acc += acc2;
    acc += __shfl_xor(acc, 16);
    acc += __shfl_xor(acc, 32);   // every lane now holds G2[ng][lane&15]
    // logits: c = lane&31 ; lg = sum_f G2[f] * W2[f][c]
    float lg = 0.0f;
#pragma unroll
    for (int fq = 0; fq < HIDDEN; fq++)
      lg += __shfl(acc, fq) * W2s[fq][cl];
    // softmax across the 32-lane group
    float m = lg;
#pragma unroll
    for (int off = 16; off >= 1; off >>= 1) m = fmaxf(m, __shfl_xor(m, off));
    const float ex = __expf(lg - m);
    float ss = ex;
#pragma unroll
    for (int off = 16; off >= 1; off >>= 1) ss += __shfl_xor(ss, off);
    if (lane < 32) O[(size_t)ng * N_CLASSES + cl] = ex / ss;
  }
}

// ================= fallback atomic path (small ws) =================
__launch_bounds__(256)
__global__ void gemm1_dropout_fb(const float* __restrict__ X,
                                 const float* __restrict__ W1,
                                 float* __restrict__ H1,
                                 uint32_t kd0, uint32_t kd1) {
  __shared__ float W1s[F_IN][HIDDEN];
  const int tid = threadIdx.x;
  for (int i = tid; i < (F_IN * HIDDEN) / 4; i += 256)
    ((float4*)W1s)[i] = ((const float4*)W1)[i];
  __syncthreads();
  const int n = blockIdx.x * 256 + tid;
  if (n >= N_NODES) return;
  float acc[HIDDEN];
#pragma unroll
  for (int j = 0; j < HIDDEN; j++) acc[j] = 0.0f;
  const float4* Xrow = (const float4*)(X + (size_t)n * F_IN);
  const uint32_t jbase = (uint32_t)n * F_IN;
  for (int cc = 0; cc < F_IN / 4; cc++) {
    float4 xv = Xrow[cc];
    float xs[4] = {xv.x, xv.y, xv.z, xv.w};
#pragma unroll
    for (int e = 0; e < 4; e++) {
      const int f = cc * 4 + e;
      const float x = keep_bit(kd0, kd1, jbase + (uint32_t)f) ? xs[e] * 2.0f : 0.0f;
      const float* wr = W1s[f];
#pragma unroll
      for (int j = 0; j < HIDDEN; j++) acc[j] += x * wr[j];
    }
  }
  float4* out = (float4*)(H1 + (size_t)n * HIDDEN);
#pragma unroll
  for (int q = 0; q < HIDDEN / 4; q++)
    out[q] = make_float4(acc[q * 4], acc[q * 4 + 1], acc[q * 4 + 2], acc[q * 4 + 3]);
}

__launch_bounds__(256)
__global__ void spmm1_atomic(const int* __restrict__ src, const int* __restrict__ dst,
                             const float* __restrict__ w, const float* __restrict__ H1,
                             float* __restrict__ H2) {
  const long long t = (long long)blockIdx.x * 256 + threadIdx.x;
  if (t >= (long long)N_EDGES * 4) return;
  const int e = (int)(t >> 2);
  const int q = (int)(t & 3);
  const float we = w[e];
  const float4 h = ((const float4*)(H1 + (size_t)src[e] * HIDDEN))[q];
  float* o = H2 + (size_t)dst[e] * HIDDEN + q * 4;
  unsafeAtomicAdd(o + 0, we * h.x);
  unsafeAtomicAdd(o + 1, we * h.y);
  unsafeAtomicAdd(o + 2, we * h.z);
  unsafeAtomicAdd(o + 3, we * h.w);
}

__launch_bounds__(256)
__global__ void gemm2_dropout(const float* __restrict__ H2,
                              const float* __restrict__ W2,
                              float* __restrict__ H3,
                              uint32_t kd0, uint32_t kd1) {
  __shared__ float W2s[HIDDEN][N_CLASSES];
  const int tid = threadIdx.x;
  for (int i = tid; i < (HIDDEN * N_CLASSES) / 4; i += 256)
    ((float4*)W2s)[i] = ((const float4*)W2)[i];
  __syncthreads();
  const int n = blockIdx.x * 256 + tid;
  if (n >= N_NODES) return;
  float acc[N_CLASSES];
#pragma unroll
  for (int j = 0; j < N_CLASSES; j++) acc[j] = 0.0f;
  const float4* hrow = (const float4*)(H2 + (size_t)n * HIDDEN);
  const uint32_t jbase = (uint32_t)n * HIDDEN;
#pragma unroll
  for (int qq = 0; qq < HIDDEN / 4; qq++) {
    float4 hv = hrow[qq];
    float hs[4] = {hv.x, hv.y, hv.z, hv.w};
#pragma unroll
    for (int e = 0; e < 4; e++) {
      const int cc = qq * 4 + e;
      float h = fmaxf(hs[e], 0.0f);
      h = keep_bit(kd0, kd1, jbase + (uint32_t)cc) ? h * 2.0f : 0.0f;
      const float* wr = W2s[cc];
#pragma unroll
      for (int j = 0; j < N_CLASSES; j++) acc[j] += h * wr[j];
    }
  }
  float4* out = (float4*)(H3 + (size_t)n * N_CLASSES);
#pragma unroll
  for (int q = 0; q < N_CLASSES / 4; q++)
    out[q] = make_float4(acc[q * 4], acc[q * 4 + 1], acc[q * 4 + 2], acc[q * 4 + 3]);
}

__launch_bounds__(256)
__global__ void spmm2_atomic(const int* __restrict__ src, const int* __restrict__ dst,
                             const float* __restrict__ w, const float* __restrict__ H3,
                             float* __restrict__ O) {
  const long long t = (long long)blockIdx.x * 256 + threadIdx.x;
  if (t >= (long long)N_EDGES * 8) return;
  const int e = (int)(t >> 3);
  const int q = (int)(t & 7);
  const float we = w[e];
  const float4 h = ((const float4*)(H3 + (size_t)src[e] * N_CLASSES))[q];
  float* o = O + (size_t)dst[e] * N_CLASSES + q * 4;
  unsafeAtomicAdd(o + 0, we * h.x);
  unsafeAtomicAdd(o + 1, we * h.y);
  unsafeAtomicAdd(o + 2, we * h.z);
  unsafeAtomicAdd(o + 3, we * h.w);
}

__launch_bounds__(256)
__global__ void softmax_rows(float* __restrict__ O) {
  const int n = blockIdx.x * 256 + threadIdx.x;
  if (n >= N_NODES) return;
  float4* row = (float4*)(O + (size_t)n * N_CLASSES);
  float v[N_CLASSES];
#pragma unroll
  for (int q = 0; q < N_CLASSES / 4; q++) {
    float4 t = row[q];
    v[q * 4 + 0] = t.x; v[q * 4 + 1] = t.y; v[q * 4 + 2] = t.z; v[q * 4 + 3] = t.w;
  }
  float m = v[0];
#pragma unroll
  for (int j = 1; j < N_CLASSES; j++) m = fmaxf(m, v[j]);
  float s = 0.0f;
#pragma unroll
  for (int j = 0; j < N_CLASSES; j++) { v[j] = __expf(v[j] - m); s += v[j]; }
  const float inv = 1.0f / s;
#pragma unroll
  for (int q = 0; q < N_CLASSES / 4; q++)
    row[q] = make_float4(v[q * 4] * inv, v[q * 4 + 1] * inv,
                         v[q * 4 + 2] * inv, v[q * 4 + 3] * inv);
}

// ---------------- host ----------------
extern "C" void kernel_launch(void* const* d_in, const int* in_sizes, int n_in,
                              void* d_out, int out_size, void* d_ws, size_t ws_size,
                              hipStream_t stream) {
  const float* X    = (const float*)d_in[0];
  const int*   esrc = (const int*)d_in[1];
  const int*   edst = (const int*)d_in[2];
  const float* ew   = (const float*)d_in[3];
  const float* W1   = (const float*)d_in[4];
  const float* W2   = (const float*)d_in[5];
  float* out = (float*)d_out;

  // JAX: key = random.key(42); kd1, kd2 = random.split(key)  (partitionable)
  uint32_t kd1_0, kd1_1, kd2_0, kd2_1;
  tf2x32_full(0u, 42u, 0u, 0u, &kd1_0, &kd1_1);
  tf2x32_full(0u, 42u, 0u, 1u, &kd2_0, &kd2_1);

  const int nb_nodes = (N_NODES + 255) / 256;       // 391 (fallback kernels)

  // workspace: ep | H1 | H2d | mask1 | gcur
  const size_t sz_ep  = (size_t)NBUK * CAP * sizeof(int2);          // 29.6 MB
  const size_t sz_H1  = (size_t)N_NODES * HIDDEN * sizeof(float);   // 6.4 MB
  const size_t sz_H2d = sz_H1;                                      // 6.4 MB
  const size_t sz_mk  = (size_t)NW_MASK * sizeof(uint32_t);         // 6.4 MB
  const size_t sz_cur = (size_t)NBUK * sizeof(int);
  const size_t need = sz_ep + sz_H1 + sz_H2d + sz_mk + sz_cur;      // ~48.9 MB

  char* p = (char*)d_ws;
  int2* ep = (int2*)p;       p += sz_ep;
  float* H1 = (float*)p;     p += sz_H1;
  float* H2d = (float*)p;    p += sz_H2d;
  uint32_t* mask1 = (uint32_t*)p; p += sz_mk;
  int* gcur = (int*)p;

  if (ws_size >= need) {
    hipMemsetAsync(gcur, 0, sz_cur, stream);
    bin_mask_fused<<<NB_BIN + NB_MSK, 256, 0, stream>>>(
        esrc, edst, ew, gcur, ep, mask1, kd1_0, kd1_1);
    gemm1_mask<<<NB_G1, 256, 0, stream>>>(X, W1, mask1, H1);
    bucket_gather1<<<NBUK, 256, 0, stream>>>(gcur, ep, H1, H2d, kd2_0, kd2_1);
    bucket_gather2<<<NBUK, 256, 0, stream>>>(gcur, ep, H2d, W2, out);
  } else {
    // fallback: atomic path (25.6 MB)
    float* fH1 = (float*)d_ws;
    float* fH2 = fH1 + (size_t)N_NODES * HIDDEN;
    float* fH3 = fH2 + (size_t)N_NODES * HIDDEN;
    hipMemsetAsync(fH2, 0, (size_t)N_NODES * HIDDEN * sizeof(float), stream);
    hipMemsetAsync(out, 0, (size_t)out_size * sizeof(float), stream);
    gemm1_dropout_fb<<<nb_nodes, 256, 0, stream>>>(X, W1, fH1, kd1_0, kd1_1);
    spmm1_atomic<<<(N_EDGES * 4) / 256, 256, 0, stream>>>(esrc, edst, ew, fH1, fH2);
    gemm2_dropout<<<nb_nodes, 256, 0, stream>>>(fH2, W2, fH3, kd2_0, kd2_1);
    spmm2_atomic<<<(N_EDGES * 8) / 256, 256, 0, stream>>>(esrc, edst, ew, fH3, out);
    softmax_rows<<<nb_nodes, 256, 0, stream>>>(out);
  }
}